// Round 13
// baseline (743.560 us; speedup 1.0000x reference)
//
#include <hip/hip_runtime.h>

constexpr int DD = 128;   // emb size
constexpr int KK = 64;    // clusters
constexpr int NBLK_C2 = 512;
constexpr int CH = 512;   // rows per scan chunk

typedef __attribute__((ext_vector_type(8))) short bf16x8;
typedef __attribute__((ext_vector_type(4))) float f32x4;

union U4 { unsigned u[4]; int4 i4; bf16x8 v; };

__device__ inline unsigned bf16_rne(float x) {
  unsigned u = __float_as_uint(x);
  u += 0x7fff + ((u >> 16) & 1);
  return u >> 16;
}
__device__ inline float bf16f(unsigned h) { return __uint_as_float(h << 16); }
__device__ inline void split2(float a, float b, unsigned& hi, unsigned& lo) {
  const unsigned h0 = bf16_rne(a), h1 = bf16_rne(b);
  const unsigned l0 = bf16_rne(a - bf16f(h0)), l1 = bf16_rne(b - bf16f(h1));
  hi = h0 | (h1 << 16);
  lo = l0 | (l1 << 16);
}

// ---- weight prep: frag-ordered split bf16. out idx = ((ks*nt+t)*64+l)*4+j ---
__global__ void k_prepW(const float* __restrict__ W, unsigned* __restrict__ Whi,
                        unsigned* __restrict__ Wlo) {  // 128x128, nt=8
  const int id = blockIdx.x * 256 + threadIdx.x;  // 8192
  const int j = id & 3, l = (id >> 2) & 63, t = (id >> 8) & 7, ks = id >> 11;
  const int k0 = 32 * ks + 8 * (l >> 4) + 2 * j;
  const int col = 16 * t + (l & 15);
  const float e0 = W[k0 * 128 + col], e1 = W[(k0 + 1) * 128 + col];
  unsigned hi, lo;
  split2(e0, e1, hi, lo);
  Whi[id] = hi;
  Wlo[id] = lo;
}

__global__ void k_prepWs(const float* __restrict__ W, unsigned* __restrict__ Wf) {
  const int id = blockIdx.x * 256 + threadIdx.x;  // 4096 (128x64, nt=4)
  const int j = id & 3, l = (id >> 2) & 63, t = (id >> 8) & 3, ks = id >> 10;
  const int k0 = 32 * ks + 8 * (l >> 4) + 2 * j;
  const int col = 16 * t + (l & 15);
  const unsigned h0 = bf16_rne(W[k0 * 64 + col]);
  const unsigned h1 = bf16_rne(W[(k0 + 1) * 64 + col]);
  Wf[id] = h0 | (h1 << 16);
}

// ---- M prep: 64x128 fp32 -> split-bf16 frags (nt=8, 2 k-steps) ------------
__global__ void k_prepM(const float* __restrict__ M, unsigned* __restrict__ Mhi,
                        unsigned* __restrict__ Mlo) {
  const int id = blockIdx.x * 256 + threadIdx.x;  // 4096
  const int j = id & 3, l = (id >> 2) & 63, t = (id >> 8) & 7, ks = id >> 11;
  const int k0 = 32 * ks + 8 * (l >> 4) + 2 * j;
  const int col = 16 * t + (l & 15);
  unsigned hi, lo;
  split2(M[k0 * 128 + col], M[(k0 + 1) * 128 + col], hi, lo);
  Mhi[id] = hi;
  Mlo[id] = lo;
}

// ---------------- Y(bf16) = X @ W via MFMA bf16x3 split ---------------------
// hi frags in LDS (32 KB -> 4 blocks/CU); lo frags read from global (L2-hot).
__global__ __launch_bounds__(512) void k_gemm_mfma(const float* __restrict__ X,
                                                   const unsigned* __restrict__ Whi,
                                                   const unsigned* __restrict__ Wlo,
                                                   unsigned short* __restrict__ Yb,
                                                   int n) {
  __shared__ unsigned sb[8192];  // hi only, 32 KB
  {
    const int t = threadIdx.x;
    uint4* d0 = (uint4*)sb;
    const uint4* s0 = (const uint4*)Whi;
#pragma unroll
    for (int i = 0; i < 4; ++i) d0[t + 512 * i] = s0[t + 512 * i];
  }
  __syncthreads();
  const int wave = threadIdx.x >> 6, lane = threadIdx.x & 63;
  const int l15 = lane & 15, lhi = lane >> 4;
  const int row0 = blockIdx.x * 256 + wave * 32;
  if (row0 >= n) return;
  f32x4 acc[2][8];
#pragma unroll
  for (int rt = 0; rt < 2; ++rt)
#pragma unroll
    for (int t = 0; t < 8; ++t) acc[rt][t] = (f32x4){0.f, 0.f, 0.f, 0.f};
#pragma unroll
  for (int ks = 0; ks < 4; ++ks) {
    U4 ah[2], al[2];
#pragma unroll
    for (int rt = 0; rt < 2; ++rt) {
      int r = row0 + rt * 16 + l15;
      if (r >= n) r = n - 1;
      const float4 x0 = *(const float4*)&X[(size_t)r * DD + ks * 32 + lhi * 8];
      const float4 x1 = *(const float4*)&X[(size_t)r * DD + ks * 32 + lhi * 8 + 4];
      split2(x0.x, x0.y, ah[rt].u[0], al[rt].u[0]);
      split2(x0.z, x0.w, ah[rt].u[1], al[rt].u[1]);
      split2(x1.x, x1.y, ah[rt].u[2], al[rt].u[2]);
      split2(x1.z, x1.w, ah[rt].u[3], al[rt].u[3]);
    }
#pragma unroll
    for (int t = 0; t < 8; ++t) {
      U4 bh, bl;
      const int off = ((ks * 8 + t) * 64 + lane) * 4;
      bh.i4 = *(const int4*)&sb[off];
      bl.i4 = *(const int4*)&Wlo[off];   // global, L2-resident, coalesced
#pragma unroll
      for (int rt = 0; rt < 2; ++rt) {
        acc[rt][t] = __builtin_amdgcn_mfma_f32_16x16x32_bf16(ah[rt].v, bh.v, acc[rt][t], 0, 0, 0);
        acc[rt][t] = __builtin_amdgcn_mfma_f32_16x16x32_bf16(al[rt].v, bh.v, acc[rt][t], 0, 0, 0);
        acc[rt][t] = __builtin_amdgcn_mfma_f32_16x16x32_bf16(ah[rt].v, bl.v, acc[rt][t], 0, 0, 0);
      }
    }
  }
#pragma unroll
  for (int rt = 0; rt < 2; ++rt)
#pragma unroll
    for (int rr = 0; rr < 4; ++rr) {
      const int row = row0 + rt * 16 + lhi * 4 + rr;
      if (row < n) {
#pragma unroll
        for (int t = 0; t < 8; ++t)
          Yb[(size_t)row * DD + t * 16 + l15] =
              (unsigned short)bf16_rne(acc[rt][t][rr]);
      }
    }
}

// ---------------- CSR build: histogram -> scan -> scatter ------------------
__global__ void k_hist(const int* __restrict__ er, int* __restrict__ cnt, int E) {
  for (long e = (long)blockIdx.x * blockDim.x + threadIdx.x; e < E;
       e += (long)gridDim.x * blockDim.x)
    atomicAdd(&cnt[er[e]], 1);
}

__global__ __launch_bounds__(256) void k_chunksum(const int* __restrict__ cnt,
                                                  int* __restrict__ csum, int n) {
  const int c = blockIdx.x, t = threadIdx.x;
  const int i0 = c * CH + 2 * t;
  int s2 = 0;
  if (i0 < n) s2 += cnt[i0];
  if (i0 + 1 < n) s2 += cnt[i0 + 1];
#pragma unroll
  for (int off = 32; off >= 1; off >>= 1) s2 += __shfl_xor(s2, off);
  __shared__ int ws_[4];
  if ((t & 63) == 0) ws_[t >> 6] = s2;
  __syncthreads();
  if (t == 0) csum[c] = ws_[0] + ws_[1] + ws_[2] + ws_[3];
}

__global__ __launch_bounds__(256) void k_chunkscan(const int* __restrict__ csum,
                                                   int* __restrict__ coff, int nch) {
  __shared__ int s[256];
  const int t = threadIdx.x;
  const int v = (t < nch) ? csum[t] : 0;
  s[t] = v;
  __syncthreads();
  for (int off = 1; off < 256; off <<= 1) {
    const int u = (t >= off) ? s[t - off] : 0;
    __syncthreads();
    s[t] += u;
    __syncthreads();
  }
  coff[t] = s[t] - v;   // exclusive
}

__global__ __launch_bounds__(256) void k_rowptr(const int* __restrict__ cnt,
                                                const int* __restrict__ coff,
                                                int* __restrict__ rowptr,
                                                int n, int E) {
  const int c = blockIdx.x, t = threadIdx.x;
  const int i0 = c * CH + 2 * t, i1 = i0 + 1;
  const int v0 = (i0 < n) ? cnt[i0] : 0;
  const int v1 = (i1 < n) ? cnt[i1] : 0;
  __shared__ int s[256];
  const int s2 = v0 + v1;
  s[t] = s2;
  __syncthreads();
  for (int off = 1; off < 256; off <<= 1) {
    const int u = (t >= off) ? s[t - off] : 0;
    __syncthreads();
    s[t] += u;
    __syncthreads();
  }
  const int excl = s[t] - s2 + coff[c];
  if (i0 < n) rowptr[i0] = excl;
  if (i1 < n) rowptr[i1] = excl + v0;
  if (c == 0 && t == 0) rowptr[n] = E;
}

// scatter {col, val} as one 8B record -> single dirty line per edge
__global__ void k_scatter(const int* __restrict__ er, const int* __restrict__ ec,
                          const float* __restrict__ ev,
                          const int* __restrict__ rowptr, int* __restrict__ cur,
                          int2* __restrict__ erec, int E) {
  for (long e = (long)blockIdx.x * blockDim.x + threadIdx.x; e < E;
       e += (long)gridDim.x * blockDim.x) {
    const int r = er[e];
    const int pos = rowptr[r] + atomicAdd(&cur[r], 1);
    erec[pos] = make_int2(ec[e], __float_as_int(ev[e]));
  }
}

// ---------------- SPMM (CSR): one wave per row, bf16 gather, 8x MLP -------
__global__ __launch_bounds__(256) void k_spmm_csr(const int* __restrict__ rowptr,
                                                  const int2* __restrict__ erec,
                                                  const unsigned* __restrict__ Yb,
                                                  float* __restrict__ Xo, int n) {
  const int lane = threadIdx.x & 63;
  const int c0 = 2 * lane;
  const long gw = (long)blockIdx.x * 4 + (threadIdx.x >> 6);
  const long nw = (long)gridDim.x * 4;
  for (long row = gw; row < n; row += nw) {
    const int b = rowptr[row], e2 = rowptr[row + 1];  // uniform -> s_load
    float a0[8], a1[8];
#pragma unroll
    for (int i = 0; i < 8; ++i) { a0[i] = 0.f; a1[i] = 0.f; }
    int e = b;
    for (; e + 8 <= e2; e += 8) {  // 8 independent gathers in flight
      int2 rr[8];
      unsigned qq[8];
#pragma unroll
      for (int i = 0; i < 8; ++i) rr[i] = erec[e + i];
#pragma unroll
      for (int i = 0; i < 8; ++i) qq[i] = Yb[(size_t)rr[i].x * (DD / 2) + lane];
#pragma unroll
      for (int i = 0; i < 8; ++i) {
        const float v = __int_as_float(rr[i].y);
        a0[i] = fmaf(v, __uint_as_float(qq[i] << 16), a0[i]);
        a1[i] = fmaf(v, __uint_as_float(qq[i] & 0xffff0000u), a1[i]);
      }
    }
    for (; e + 2 <= e2; e += 2) {
      const int2 r0 = erec[e], r1 = erec[e + 1];
      const unsigned q0 = Yb[(size_t)r0.x * (DD / 2) + lane];
      const unsigned q1 = Yb[(size_t)r1.x * (DD / 2) + lane];
      const float v0 = __int_as_float(r0.y), v1 = __int_as_float(r1.y);
      a0[0] = fmaf(v0, __uint_as_float(q0 << 16), a0[0]);
      a1[0] = fmaf(v0, __uint_as_float(q0 & 0xffff0000u), a1[0]);
      a0[1] = fmaf(v1, __uint_as_float(q1 << 16), a0[1]);
      a1[1] = fmaf(v1, __uint_as_float(q1 & 0xffff0000u), a1[1]);
    }
    if (e < e2) {
      const int2 r0 = erec[e];
      const float v = __int_as_float(r0.y);
      const unsigned q = Yb[(size_t)r0.x * (DD / 2) + lane];
      a0[0] = fmaf(v, __uint_as_float(q << 16), a0[0]);
      a1[0] = fmaf(v, __uint_as_float(q & 0xffff0000u), a1[0]);
    }
    const float s0 = ((a0[0] + a0[1]) + (a0[2] + a0[3])) + ((a0[4] + a0[5]) + (a0[6] + a0[7]));
    const float s1 = ((a1[0] + a1[1]) + (a1[2] + a1[3])) + ((a1[4] + a1[5]) + (a1[6] + a1[7]));
    *(float2*)&Xo[(size_t)row * DD + c0] = make_float2(s0, s1);
  }
}

// ---------------- fused: H1 = softmax(relu(X@Wi1 + X) @ Wi2), MFMA --------
// Wi1-hi in LDS; Wi1-lo and Wi2 frags from global (L2-hot).
// LDS = 32 + 34 = 66 KB -> 2 blocks/CU (4 waves/SIMD).
__global__ __launch_bounds__(512) void k_c1_mfma(const float* __restrict__ X,
                                                 const unsigned* __restrict__ W1hi,
                                                 const unsigned* __restrict__ W1lo,
                                                 const unsigned* __restrict__ W2f,
                                                 const float* __restrict__ adj,
                                                 float* __restrict__ H1g,
                                                 float* __restrict__ trow, int n) {
  __shared__ unsigned s1[8192];         // Wi1 hi frags, 32 KB
  __shared__ unsigned h1s[8 * 16 * 68]; // 8 waves x (16 rows x 68 u32), 34 KB
  {
    const int t = threadIdx.x;
    uint4* d0 = (uint4*)s1;
    const uint4* sA = (const uint4*)W1hi;
#pragma unroll
    for (int i = 0; i < 4; ++i) d0[t + 512 * i] = sA[t + 512 * i];
  }
  __syncthreads();
  const int wave = threadIdx.x >> 6, lane = threadIdx.x & 63;
  const int l15 = lane & 15, lhi = lane >> 4;
  unsigned* __restrict__ h1w = h1s + wave * (16 * 68);
  const int row0 = blockIdx.x * 128 + wave * 16;
  if (row0 >= n) return;

  // ---- P1: acc1 = x @ Wi1 (split bf16, 3 MFMA) ----
  U4 ah[4], al[4];
#pragma unroll
  for (int ks = 0; ks < 4; ++ks) {
    int r = row0 + l15;
    if (r >= n) r = n - 1;
    const float4 x0 = *(const float4*)&X[(size_t)r * DD + ks * 32 + lhi * 8];
    const float4 x1 = *(const float4*)&X[(size_t)r * DD + ks * 32 + lhi * 8 + 4];
    split2(x0.x, x0.y, ah[ks].u[0], al[ks].u[0]);
    split2(x0.z, x0.w, ah[ks].u[1], al[ks].u[1]);
    split2(x1.x, x1.y, ah[ks].u[2], al[ks].u[2]);
    split2(x1.z, x1.w, ah[ks].u[3], al[ks].u[3]);
  }
  f32x4 acc1[8];
#pragma unroll
  for (int t = 0; t < 8; ++t) acc1[t] = (f32x4){0.f, 0.f, 0.f, 0.f};
#pragma unroll
  for (int ks = 0; ks < 4; ++ks) {
#pragma unroll
    for (int t = 0; t < 8; ++t) {
      U4 bh, bl;
      const int off = ((ks * 8 + t) * 64 + lane) * 4;
      bh.i4 = *(const int4*)&s1[off];
      bl.i4 = *(const int4*)&W1lo[off];   // global, L2-resident
      acc1[t] = __builtin_amdgcn_mfma_f32_16x16x32_bf16(ah[ks].v, bh.v, acc1[t], 0, 0, 0);
      acc1[t] = __builtin_amdgcn_mfma_f32_16x16x32_bf16(al[ks].v, bh.v, acc1[t], 0, 0, 0);
      acc1[t] = __builtin_amdgcn_mfma_f32_16x16x32_bf16(ah[ks].v, bl.v, acc1[t], 0, 0, 0);
    }
  }

  // ---- P2: +x, relu, pack single bf16 into wave-private LDS (stride 136) --
  unsigned short* __restrict__ h16 = (unsigned short*)h1w;
#pragma unroll
  for (int rr = 0; rr < 4; ++rr) {
    int row = row0 + 4 * lhi + rr;
    if (row >= n) row = n - 1;
    const float* __restrict__ xr = X + (size_t)row * DD;
#pragma unroll
    for (int t = 0; t < 8; ++t) {
      float v = acc1[t][rr] + xr[16 * t + l15];
      v = fmaxf(v, 0.f);
      h16[(4 * lhi + rr) * 136 + 16 * t + l15] = (unsigned short)bf16_rne(v);
    }
  }

  // ---- P3: z = H1a @ Wi2 (single bf16) ----
  f32x4 acc3[4];
#pragma unroll
  for (int t = 0; t < 4; ++t) acc3[t] = (f32x4){0.f, 0.f, 0.f, 0.f};
#pragma unroll
  for (int ks = 0; ks < 4; ++ks) {
    U4 a3;
    a3.i4 = *(const int4*)&h1w[l15 * 68 + ks * 16 + lhi * 4];
#pragma unroll
    for (int t = 0; t < 4; ++t) {
      U4 b3;
      b3.i4 = *(const int4*)&W2f[((ks * 4 + t) * 64 + lane) * 4];  // global
      acc3[t] = __builtin_amdgcn_mfma_f32_16x16x32_bf16(a3.v, b3.v, acc3[t], 0, 0, 0);
    }
  }

  // ---- P4: row softmax (64 cols = 4 tiles x 16 lanes) ----
#pragma unroll
  for (int rr = 0; rr < 4; ++rr) {
    const int row = row0 + 4 * lhi + rr;
    float z0 = acc3[0][rr], z1 = acc3[1][rr], z2 = acc3[2][rr], z3 = acc3[3][rr];
    float m = fmaxf(fmaxf(z0, z1), fmaxf(z2, z3));
#pragma unroll
    for (int off = 8; off >= 1; off >>= 1) m = fmaxf(m, __shfl_xor(m, off));
    const float p0 = expf(z0 - m), p1 = expf(z1 - m);
    const float p2 = expf(z2 - m), p3 = expf(z3 - m);
    float s = p0 + p1 + p2 + p3;
#pragma unroll
    for (int off = 8; off >= 1; off >>= 1) s += __shfl_xor(s, off);
    const float inv = 1.0f / s;
    if (row < n) {
      float* __restrict__ hr = H1g + (size_t)row * KK;
      hr[l15] = p0 * inv;
      hr[16 + l15] = p1 * inv;
      hr[32 + l15] = p2 * inv;
      hr[48 + l15] = p3 * inv;
      if (l15 == 0) {
        const float a = adj[row];
        trow[row] = a / (a + 1e-8f);
      }
    }
  }
}

// ---------------- per-block partial of M = (H1*t)^T @ X --------------------
__global__ __launch_bounds__(1024, 4) void k_c2(const float* __restrict__ X,
                                                const float* __restrict__ trow,
                                                const float* __restrict__ H1g,
                                                float* __restrict__ Mpart, int n) {
  __shared__ float cmb[3 * 4 * 16 * 2 * 64];  // 96 KB
  const int t = threadIdx.x;
  const int wave = t >> 6, lane = t & 63;
  const int rg = wave >> 2, kg = wave & 3;
  const int kb = kg * 16;
  const int d0 = 2 * lane;
  float macc[16][2];
#pragma unroll
  for (int j = 0; j < 16; ++j) { macc[j][0] = 0.f; macc[j][1] = 0.f; }
  const int bx = blockIdx.x;
  for (long row = (long)bx + 512L * rg; row < n; row += 2048L) {
    const int r = __builtin_amdgcn_readfirstlane((int)row);
    const float tr = trow[r];                         // s_load
    const float2 xv = *(const float2*)&X[(size_t)r * DD + d0];
    const float px0 = tr * xv.x, px1 = tr * xv.y;
    const float* __restrict__ hrow = H1g + (size_t)r * KK + kb;  // s_loads
#pragma unroll
    for (int j = 0; j < 16; ++j) {
      const float hj = hrow[j];
      macc[j][0] = fmaf(hj, px0, macc[j][0]);
      macc[j][1] = fmaf(hj, px1, macc[j][1]);
    }
  }
  if (rg > 0) {
    float* __restrict__ dst = cmb + ((rg - 1) * 4 + kg) * (16 * 2 * 64);
#pragma unroll
    for (int j = 0; j < 16; ++j) {
      dst[(2 * j + 0) * 64 + lane] = macc[j][0];
      dst[(2 * j + 1) * 64 + lane] = macc[j][1];
    }
  }
  __syncthreads();
  if (rg == 0) {
#pragma unroll
    for (int g = 0; g < 3; ++g) {
      const float* __restrict__ src = cmb + (g * 4 + kg) * (16 * 2 * 64);
#pragma unroll
      for (int j = 0; j < 16; ++j) {
        macc[j][0] += src[(2 * j + 0) * 64 + lane];
        macc[j][1] += src[(2 * j + 1) * 64 + lane];
      }
    }
    float* __restrict__ mp = Mpart + (size_t)bx * (KK * DD);
#pragma unroll
    for (int j = 0; j < 16; ++j)
      *(float2*)&mp[(kb + j) * DD + d0] = make_float2(macc[j][0], macc[j][1]);
  }
}

// ---------------- two-stage fixed-order reduction of M partials ------------
__global__ void k_dred1(const float* __restrict__ Mpart, float* __restrict__ Mp2) {
  const int j = blockIdx.x * blockDim.x + threadIdx.x;  // 262144 threads
  const int i = j & (KK * DD - 1);
  const int c = j >> 13;
  float s = 0.f;
#pragma unroll
  for (int q = 0; q < 16; ++q)
    s += Mpart[(size_t)(c * 16 + q) * (KK * DD) + i];
  Mp2[(size_t)c * (KK * DD) + i] = s;
}

__global__ void k_dred2(const float* __restrict__ Mp2, float* __restrict__ Mg) {
  const int i = blockIdx.x * blockDim.x + threadIdx.x;  // 8192 threads
  float s = 0.f;
#pragma unroll
  for (int c = 0; c < 32; ++c) s += Mp2[(size_t)c * (KK * DD) + i];
  Mg[i] = s;
}

// ------- h = H1 @ M (split-bf16 MFMA); x = h + x; l2-normed outputs --------
__global__ __launch_bounds__(512) void k_fin_mfma(const float* __restrict__ H1g,
                                                  const unsigned* __restrict__ Mhi,
                                                  const unsigned* __restrict__ Mlo,
                                                  const float* __restrict__ emb,
                                                  float* __restrict__ Xb,
                                                  float* __restrict__ out,
                                                  int n, int first) {
  __shared__ unsigned sm[2 * 4096];  // M frags hi|lo, 32 KB
  {
    const int t = threadIdx.x;
    uint4* d0 = (uint4*)sm;
    const uint4* s0 = (const uint4*)Mhi;
#pragma unroll
    for (int i = 0; i < 2; ++i) d0[t + 512 * i] = s0[t + 512 * i];
    uint4* d1 = (uint4*)(sm + 4096);
    const uint4* s1 = (const uint4*)Mlo;
#pragma unroll
    for (int i = 0; i < 2; ++i) d1[t + 512 * i] = s1[t + 512 * i];
  }
  __syncthreads();
  const int wave = threadIdx.x >> 6, lane = threadIdx.x & 63;
  const int l15 = lane & 15, lhi = lane >> 4;
  const size_t hoff = (size_t)n * DD;
  const int row0 = blockIdx.x * 128 + wave * 16;
  if (row0 >= n) return;

  // A frags: 16 H1 rows, K=64, split hi/lo
  U4 ah[2], al[2];
  {
    int ra = row0 + l15;
    if (ra >= n) ra = n - 1;
    const float* __restrict__ hp = H1g + (size_t)ra * KK;
#pragma unroll
    for (int ks = 0; ks < 2; ++ks) {
      const float4 x0 = *(const float4*)&hp[ks * 32 + lhi * 8];
      const float4 x1 = *(const float4*)&hp[ks * 32 + lhi * 8 + 4];
      split2(x0.x, x0.y, ah[ks].u[0], al[ks].u[0]);
      split2(x0.z, x0.w, ah[ks].u[1], al[ks].u[1]);
      split2(x1.x, x1.y, ah[ks].u[2], al[ks].u[2]);
      split2(x1.z, x1.w, ah[ks].u[3], al[ks].u[3]);
    }
  }
  f32x4 acc[8];
#pragma unroll
  for (int t = 0; t < 8; ++t) acc[t] = (f32x4){0.f, 0.f, 0.f, 0.f};
#pragma unroll
  for (int ks = 0; ks < 2; ++ks) {
#pragma unroll
    for (int t = 0; t < 8; ++t) {
      U4 bh, bl;
      const int off = ((ks * 8 + t) * 64 + lane) * 4;
      bh.i4 = *(const int4*)&sm[off];
      bl.i4 = *(const int4*)&sm[4096 + off];
      acc[t] = __builtin_amdgcn_mfma_f32_16x16x32_bf16(ah[ks].v, bh.v, acc[t], 0, 0, 0);
      acc[t] = __builtin_amdgcn_mfma_f32_16x16x32_bf16(al[ks].v, bh.v, acc[t], 0, 0, 0);
      acc[t] = __builtin_amdgcn_mfma_f32_16x16x32_bf16(ah[ks].v, bl.v, acc[t], 0, 0, 0);
    }
  }
  // epilogue: per row (4 per lhi-group), cols 16t+l15
#pragma unroll
  for (int rr = 0; rr < 4; ++rr) {
    const int row = row0 + 4 * lhi + rr;
    const int rc = (row < n) ? row : (n - 1);
    float hh[8], xx[8];
    float sh = 0.f, sx = 0.f;
#pragma unroll
    for (int t = 0; t < 8; ++t) {
      const float xv = Xb[(size_t)rc * DD + 16 * t + l15];
      hh[t] = acc[t][rr];
      xx[t] = hh[t] + xv;
      sh = fmaf(hh[t], hh[t], sh);
      sx = fmaf(xx[t], xx[t], sx);
    }
#pragma unroll
    for (int off = 8; off >= 1; off >>= 1) {  // reduce within 16-lane row group
      sh += __shfl_xor(sh, off);
      sx += __shfl_xor(sx, off);
    }
    const float ih = 0.5f / fmaxf(sqrtf(sh), 1e-12f);
    const float ix = (1.0f / 3.0f) / fmaxf(sqrtf(sx), 1e-12f);
    if (row < n) {
#pragma unroll
      for (int t = 0; t < 8; ++t) {
        const size_t oi = (size_t)row * DD + 16 * t + l15;
        Xb[oi] = xx[t];
        float ci, ch;
        if (first) {
          ci = emb[oi] * (1.0f / 3.0f);
          ch = 0.f;
        } else {
          ci = out[oi];
          ch = out[hoff + oi];
        }
        out[oi] = ci + xx[t] * ix;
        out[hoff + oi] = ch + hh[t] * ih;
      }
    }
  }
}

extern "C" void kernel_launch(void* const* d_in, const int* in_sizes, int n_in,
                              void* d_out, int out_size, void* d_ws, size_t ws_size,
                              hipStream_t stream) {
  const float* adj  = (const float*)d_in[0];
  const int*   erow = (const int*)d_in[1];
  const int*   ecol = (const int*)d_in[2];
  const float* eval = (const float*)d_in[3];
  const float* emb  = (const float*)d_in[4];
  const float* W0   = (const float*)d_in[5];
  const float* W1   = (const float*)d_in[6];
  const float* Wi1  = (const float*)d_in[7];
  const float* Wi2  = (const float*)d_in[8];
  const int n = in_sizes[0];
  const int E = in_sizes[1];
  float* out = (float*)d_out;

  // workspace (4B units):
  // [xb: n*DD][yb: n*DD (Ybf16 | H1 | Mpart | Mp2 | Mg)]
  // [cnt: n][rowptr: n+4][csum: 256][coff: 256][erec: E int2][trow: n]
  // [w0hi/w0lo/w1hi/w1lo/wi1hi/wi1lo: 6x8192][wi2f: 4096][mhi/mlo: 2x4096]
  float* xb    = (float*)d_ws;
  float* yb    = xb + (size_t)n * DD;
  unsigned short* Ybf = (unsigned short*)yb;
  float* H1g   = yb + (size_t)n * (DD / 2);  // after Ybf region (Ybf dead by c1)
  float* Mpart = H1g + (size_t)n * KK;
  float* Mp2   = Mpart + (size_t)NBLK_C2 * KK * DD;
  float* Mg    = Mp2 + (size_t)32 * KK * DD;
  int*   cnt    = (int*)(Mg + KK * DD);
  int*   rowptr = cnt + n;
  int*   csum   = rowptr + n + 4;
  int*   coff   = csum + 256;
  int2*  erec   = (int2*)(coff + 256);
  float* trow   = (float*)(erec + E);
  unsigned* w0hi  = (unsigned*)(trow + n);
  unsigned* w0lo  = w0hi + 8192;
  unsigned* w1hi_ = w0lo + 8192;
  unsigned* w1lo_ = w1hi_ + 8192;
  unsigned* wi1hi = w1lo_ + 8192;
  unsigned* wi1lo = wi1hi + 8192;
  unsigned* wi2f  = wi1lo + 8192;
  unsigned* mhi   = wi2f + 4096;
  unsigned* mlo   = mhi + 4096;

  const int NCH = (n + CH - 1) / CH;

  // ---- weight prep (once per launch) ----
  k_prepW<<<32, 256, 0, stream>>>(W0, w0hi, w0lo);
  k_prepW<<<32, 256, 0, stream>>>(W1, w1hi_, w1lo_);
  k_prepW<<<32, 256, 0, stream>>>(Wi1, wi1hi, wi1lo);
  k_prepWs<<<16, 256, 0, stream>>>(Wi2, wi2f);

  // ---- CSR build (once per launch; deterministic work) ----
  hipMemsetAsync(cnt, 0, (size_t)n * sizeof(int), stream);
  k_hist<<<2048, 256, 0, stream>>>(erow, cnt, E);
  k_chunksum<<<NCH, 256, 0, stream>>>(cnt, csum, n);
  k_chunkscan<<<1, 256, 0, stream>>>(csum, coff, NCH);
  k_rowptr<<<NCH, 256, 0, stream>>>(cnt, coff, rowptr, n, E);
  hipMemsetAsync(cnt, 0, (size_t)n * sizeof(int), stream);
  k_scatter<<<2048, 256, 0, stream>>>(erow, ecol, eval, rowptr, cnt, erec, E);

  const int g_gm  = (n + 255) / 256;   // 8 waves x 32 rows
  const int g_c1m = (n + 127) / 128;   // 8 waves x 16 rows
  const int g_fin = (n + 127) / 128;   // 8 waves x 16 rows

  for (int L = 0; L < 2; ++L) {
    const unsigned* Whi = (L == 0) ? w0hi : w1hi_;
    const unsigned* Wlo = (L == 0) ? w0lo : w1lo_;
    const float* Xin = (L == 0) ? emb : xb;
    k_gemm_mfma<<<g_gm, 512, 0, stream>>>(Xin, Whi, Wlo, Ybf, n);
    k_spmm_csr<<<2048, 256, 0, stream>>>(rowptr, erec, (const unsigned*)Ybf, xb, n);
    k_c1_mfma<<<g_c1m, 512, 0, stream>>>(xb, wi1hi, wi1lo, wi2f, adj, H1g, trow, n);
    k_c2<<<NBLK_C2, 1024, 0, stream>>>(xb, trow, H1g, Mpart, n);
    k_dred1<<<1024, 256, 0, stream>>>(Mpart, Mp2);
    k_dred2<<<32, 256, 0, stream>>>(Mp2, Mg);
    k_prepM<<<16, 256, 0, stream>>>(Mg, mhi, mlo);
    k_fin_mfma<<<g_fin, 512, 0, stream>>>(H1g, mhi, mlo, emb, xb, out, n, (L == 0) ? 1 : 0);
  }
}

// Round 14
// 691.107 us; speedup vs baseline: 1.0759x; 1.0759x over previous
//
#include <hip/hip_runtime.h>

constexpr int DD = 128;   // emb size
constexpr int KK = 64;    // clusters
constexpr int NBLK_C2 = 512;
constexpr int CH = 512;   // rows per scan chunk

typedef __attribute__((ext_vector_type(8))) short bf16x8;
typedef __attribute__((ext_vector_type(4))) float f32x4;

union U4 { unsigned u[4]; int4 i4; bf16x8 v; };

__device__ inline unsigned bf16_rne(float x) {
  unsigned u = __float_as_uint(x);
  u += 0x7fff + ((u >> 16) & 1);
  return u >> 16;
}
__device__ inline float bf16f(unsigned h) { return __uint_as_float(h << 16); }
__device__ inline void split2(float a, float b, unsigned& hi, unsigned& lo) {
  const unsigned h0 = bf16_rne(a), h1 = bf16_rne(b);
  const unsigned l0 = bf16_rne(a - bf16f(h0)), l1 = bf16_rne(b - bf16f(h1));
  hi = h0 | (h1 << 16);
  lo = l0 | (l1 << 16);
}

// ---- weight prep: frag-ordered split bf16. out idx = ((ks*nt+t)*64+l)*4+j ---
__global__ void k_prepW(const float* __restrict__ W, unsigned* __restrict__ Whi,
                        unsigned* __restrict__ Wlo) {  // 128x128, nt=8
  const int id = blockIdx.x * 256 + threadIdx.x;  // 8192
  const int j = id & 3, l = (id >> 2) & 63, t = (id >> 8) & 7, ks = id >> 11;
  const int k0 = 32 * ks + 8 * (l >> 4) + 2 * j;
  const int col = 16 * t + (l & 15);
  const float e0 = W[k0 * 128 + col], e1 = W[(k0 + 1) * 128 + col];
  unsigned hi, lo;
  split2(e0, e1, hi, lo);
  Whi[id] = hi;
  Wlo[id] = lo;
}

__global__ void k_prepWs(const float* __restrict__ W, unsigned* __restrict__ Wf) {
  const int id = blockIdx.x * 256 + threadIdx.x;  // 4096 (128x64, nt=4)
  const int j = id & 3, l = (id >> 2) & 63, t = (id >> 8) & 3, ks = id >> 10;
  const int k0 = 32 * ks + 8 * (l >> 4) + 2 * j;
  const int col = 16 * t + (l & 15);
  const unsigned h0 = bf16_rne(W[k0 * 64 + col]);
  const unsigned h1 = bf16_rne(W[(k0 + 1) * 64 + col]);
  Wf[id] = h0 | (h1 << 16);
}

// ---------------- Y(bf16) = X @ W via MFMA bf16x3 split ---------------------
__global__ __launch_bounds__(512) void k_gemm_mfma(const float* __restrict__ X,
                                                   const unsigned* __restrict__ Whi,
                                                   const unsigned* __restrict__ Wlo,
                                                   unsigned short* __restrict__ Yb,
                                                   int n) {
  __shared__ unsigned sb[2 * 8192];  // hi | lo, 64 KB
  {
    const int t = threadIdx.x;
    uint4* d0 = (uint4*)sb;
    const uint4* s0 = (const uint4*)Whi;
#pragma unroll
    for (int i = 0; i < 4; ++i) d0[t + 512 * i] = s0[t + 512 * i];
    uint4* d1 = (uint4*)(sb + 8192);
    const uint4* s1 = (const uint4*)Wlo;
#pragma unroll
    for (int i = 0; i < 4; ++i) d1[t + 512 * i] = s1[t + 512 * i];
  }
  __syncthreads();
  const int wave = threadIdx.x >> 6, lane = threadIdx.x & 63;
  const int l15 = lane & 15, lhi = lane >> 4;
  const int row0 = blockIdx.x * 256 + wave * 32;
  if (row0 >= n) return;
  f32x4 acc[2][8];
#pragma unroll
  for (int rt = 0; rt < 2; ++rt)
#pragma unroll
    for (int t = 0; t < 8; ++t) acc[rt][t] = (f32x4){0.f, 0.f, 0.f, 0.f};
#pragma unroll
  for (int ks = 0; ks < 4; ++ks) {
    U4 ah[2], al[2];
#pragma unroll
    for (int rt = 0; rt < 2; ++rt) {
      int r = row0 + rt * 16 + l15;
      if (r >= n) r = n - 1;
      const float4 x0 = *(const float4*)&X[(size_t)r * DD + ks * 32 + lhi * 8];
      const float4 x1 = *(const float4*)&X[(size_t)r * DD + ks * 32 + lhi * 8 + 4];
      split2(x0.x, x0.y, ah[rt].u[0], al[rt].u[0]);
      split2(x0.z, x0.w, ah[rt].u[1], al[rt].u[1]);
      split2(x1.x, x1.y, ah[rt].u[2], al[rt].u[2]);
      split2(x1.z, x1.w, ah[rt].u[3], al[rt].u[3]);
    }
#pragma unroll
    for (int t = 0; t < 8; ++t) {
      U4 bh, bl;
      const int off = ((ks * 8 + t) * 64 + lane) * 4;
      bh.i4 = *(const int4*)&sb[off];
      bl.i4 = *(const int4*)&sb[8192 + off];
#pragma unroll
      for (int rt = 0; rt < 2; ++rt) {
        acc[rt][t] = __builtin_amdgcn_mfma_f32_16x16x32_bf16(ah[rt].v, bh.v, acc[rt][t], 0, 0, 0);
        acc[rt][t] = __builtin_amdgcn_mfma_f32_16x16x32_bf16(al[rt].v, bh.v, acc[rt][t], 0, 0, 0);
        acc[rt][t] = __builtin_amdgcn_mfma_f32_16x16x32_bf16(ah[rt].v, bl.v, acc[rt][t], 0, 0, 0);
      }
    }
  }
#pragma unroll
  for (int rt = 0; rt < 2; ++rt)
#pragma unroll
    for (int rr = 0; rr < 4; ++rr) {
      const int row = row0 + rt * 16 + lhi * 4 + rr;
      if (row < n) {
#pragma unroll
        for (int t = 0; t < 8; ++t)
          Yb[(size_t)row * DD + t * 16 + l15] =
              (unsigned short)bf16_rne(acc[rt][t][rr]);
      }
    }
}

// ---------------- CSR build: histogram -> scan -> scatter ------------------
__global__ void k_hist(const int* __restrict__ er, int* __restrict__ cnt, int E) {
  for (long e = (long)blockIdx.x * blockDim.x + threadIdx.x; e < E;
       e += (long)gridDim.x * blockDim.x)
    atomicAdd(&cnt[er[e]], 1);
}

__global__ __launch_bounds__(256) void k_chunksum(const int* __restrict__ cnt,
                                                  int* __restrict__ csum, int n) {
  const int c = blockIdx.x, t = threadIdx.x;
  const int i0 = c * CH + 2 * t;
  int s2 = 0;
  if (i0 < n) s2 += cnt[i0];
  if (i0 + 1 < n) s2 += cnt[i0 + 1];
#pragma unroll
  for (int off = 32; off >= 1; off >>= 1) s2 += __shfl_xor(s2, off);
  __shared__ int ws_[4];
  if ((t & 63) == 0) ws_[t >> 6] = s2;
  __syncthreads();
  if (t == 0) csum[c] = ws_[0] + ws_[1] + ws_[2] + ws_[3];
}

__global__ __launch_bounds__(256) void k_chunkscan(const int* __restrict__ csum,
                                                   int* __restrict__ coff, int nch) {
  __shared__ int s[256];
  const int t = threadIdx.x;
  const int v = (t < nch) ? csum[t] : 0;
  s[t] = v;
  __syncthreads();
  for (int off = 1; off < 256; off <<= 1) {
    const int u = (t >= off) ? s[t - off] : 0;
    __syncthreads();
    s[t] += u;
    __syncthreads();
  }
  coff[t] = s[t] - v;   // exclusive
}

__global__ __launch_bounds__(256) void k_rowptr(const int* __restrict__ cnt,
                                                const int* __restrict__ coff,
                                                int* __restrict__ rowptr,
                                                int n, int E) {
  const int c = blockIdx.x, t = threadIdx.x;
  const int i0 = c * CH + 2 * t, i1 = i0 + 1;
  const int v0 = (i0 < n) ? cnt[i0] : 0;
  const int v1 = (i1 < n) ? cnt[i1] : 0;
  __shared__ int s[256];
  const int s2 = v0 + v1;
  s[t] = s2;
  __syncthreads();
  for (int off = 1; off < 256; off <<= 1) {
    const int u = (t >= off) ? s[t - off] : 0;
    __syncthreads();
    s[t] += u;
    __syncthreads();
  }
  const int excl = s[t] - s2 + coff[c];
  if (i0 < n) rowptr[i0] = excl;
  if (i1 < n) rowptr[i1] = excl + v0;
  if (c == 0 && t == 0) rowptr[n] = E;
}

// scatter {col, val} as one 8B record -> single dirty line per edge
__global__ void k_scatter(const int* __restrict__ er, const int* __restrict__ ec,
                          const float* __restrict__ ev,
                          const int* __restrict__ rowptr, int* __restrict__ cur,
                          int2* __restrict__ erec, int E) {
  for (long e = (long)blockIdx.x * blockDim.x + threadIdx.x; e < E;
       e += (long)gridDim.x * blockDim.x) {
    const int r = er[e];
    const int pos = rowptr[r] + atomicAdd(&cur[r], 1);
    erec[pos] = make_int2(ec[e], __float_as_int(ev[e]));
  }
}

// ---------------- SPMM (CSR): one wave per row, bf16 gather, 4x MLP -------
__global__ __launch_bounds__(256) void k_spmm_csr(const int* __restrict__ rowptr,
                                                  const int2* __restrict__ erec,
                                                  const unsigned* __restrict__ Yb,
                                                  float* __restrict__ Xo, int n) {
  const int lane = threadIdx.x & 63;
  const int c0 = 2 * lane;
  const long gw = (long)blockIdx.x * 4 + (threadIdx.x >> 6);
  const long nw = (long)gridDim.x * 4;
  for (long row = gw; row < n; row += nw) {
    const int b = rowptr[row], e2 = rowptr[row + 1];  // uniform -> s_load
    float a0 = 0.f, a1 = 0.f, b0 = 0.f, b1 = 0.f;
    float c00 = 0.f, c1 = 0.f, d0 = 0.f, d1 = 0.f;
    int e = b;
    for (; e + 4 <= e2; e += 4) {  // 4 independent gathers in flight
      const int2 r0 = erec[e], r1 = erec[e + 1];
      const int2 r2 = erec[e + 2], r3 = erec[e + 3];  // 32B uniform s_load
      const unsigned q0 = Yb[(size_t)r0.x * (DD / 2) + lane];
      const unsigned q1 = Yb[(size_t)r1.x * (DD / 2) + lane];
      const unsigned q2 = Yb[(size_t)r2.x * (DD / 2) + lane];
      const unsigned q3 = Yb[(size_t)r3.x * (DD / 2) + lane];
      const float v0 = __int_as_float(r0.y), v1 = __int_as_float(r1.y);
      const float v2 = __int_as_float(r2.y), v3 = __int_as_float(r3.y);
      a0 = fmaf(v0, __uint_as_float(q0 << 16), a0);
      a1 = fmaf(v0, __uint_as_float(q0 & 0xffff0000u), a1);
      b0 = fmaf(v1, __uint_as_float(q1 << 16), b0);
      b1 = fmaf(v1, __uint_as_float(q1 & 0xffff0000u), b1);
      c00 = fmaf(v2, __uint_as_float(q2 << 16), c00);
      c1 = fmaf(v2, __uint_as_float(q2 & 0xffff0000u), c1);
      d0 = fmaf(v3, __uint_as_float(q3 << 16), d0);
      d1 = fmaf(v3, __uint_as_float(q3 & 0xffff0000u), d1);
    }
    for (; e + 2 <= e2; e += 2) {
      const int2 r0 = erec[e], r1 = erec[e + 1];
      const float v0 = __int_as_float(r0.y), v1 = __int_as_float(r1.y);
      const unsigned q0 = Yb[(size_t)r0.x * (DD / 2) + lane];
      const unsigned q1 = Yb[(size_t)r1.x * (DD / 2) + lane];
      a0 = fmaf(v0, __uint_as_float(q0 << 16), a0);
      a1 = fmaf(v0, __uint_as_float(q0 & 0xffff0000u), a1);
      b0 = fmaf(v1, __uint_as_float(q1 << 16), b0);
      b1 = fmaf(v1, __uint_as_float(q1 & 0xffff0000u), b1);
    }
    if (e < e2) {
      const int2 r0 = erec[e];
      const float v = __int_as_float(r0.y);
      const unsigned q = Yb[(size_t)r0.x * (DD / 2) + lane];
      a0 = fmaf(v, __uint_as_float(q << 16), a0);
      a1 = fmaf(v, __uint_as_float(q & 0xffff0000u), a1);
    }
    *(float2*)&Xo[(size_t)row * DD + c0] =
        make_float2((a0 + b0) + (c00 + d0), (a1 + b1) + (c1 + d1));
  }
}

// ---------------- fused: H1 = softmax(relu(X@Wi1 + X) @ Wi2), MFMA --------
__global__ __launch_bounds__(512) void k_c1_mfma(const float* __restrict__ X,
                                                 const unsigned* __restrict__ W1hi,
                                                 const unsigned* __restrict__ W1lo,
                                                 const unsigned* __restrict__ W2f,
                                                 const float* __restrict__ adj,
                                                 float* __restrict__ H1g,
                                                 float* __restrict__ trow, int n) {
  __shared__ unsigned s1[2 * 8192];     // Wi1 frags hi|lo, 64 KB
  __shared__ unsigned s2[4096];         // Wi2 frags, 16 KB
  __shared__ unsigned h1s[8 * 16 * 68]; // 8 waves x (16 rows x 68 u32), 34 KB
  {
    const int t = threadIdx.x;
    uint4* d0 = (uint4*)s1;
    const uint4* sA = (const uint4*)W1hi;
    const uint4* sB = (const uint4*)W1lo;
#pragma unroll
    for (int i = 0; i < 4; ++i) d0[t + 512 * i] = sA[t + 512 * i];
    uint4* d1 = (uint4*)(s1 + 8192);
#pragma unroll
    for (int i = 0; i < 4; ++i) d1[t + 512 * i] = sB[t + 512 * i];
    uint4* d2 = (uint4*)s2;
    const uint4* sC = (const uint4*)W2f;
#pragma unroll
    for (int i = 0; i < 2; ++i) d2[t + 512 * i] = sC[t + 512 * i];
  }
  __syncthreads();
  const int wave = threadIdx.x >> 6, lane = threadIdx.x & 63;
  const int l15 = lane & 15, lhi = lane >> 4;
  unsigned* __restrict__ h1w = h1s + wave * (16 * 68);
  const int row0 = blockIdx.x * 128 + wave * 16;
  if (row0 >= n) return;

  // ---- P1: acc1 = x @ Wi1 (split bf16, 3 MFMA) ----
  U4 ah[4], al[4];
#pragma unroll
  for (int ks = 0; ks < 4; ++ks) {
    int r = row0 + l15;
    if (r >= n) r = n - 1;
    const float4 x0 = *(const float4*)&X[(size_t)r * DD + ks * 32 + lhi * 8];
    const float4 x1 = *(const float4*)&X[(size_t)r * DD + ks * 32 + lhi * 8 + 4];
    split2(x0.x, x0.y, ah[ks].u[0], al[ks].u[0]);
    split2(x0.z, x0.w, ah[ks].u[1], al[ks].u[1]);
    split2(x1.x, x1.y, ah[ks].u[2], al[ks].u[2]);
    split2(x1.z, x1.w, ah[ks].u[3], al[ks].u[3]);
  }
  f32x4 acc1[8];
#pragma unroll
  for (int t = 0; t < 8; ++t) acc1[t] = (f32x4){0.f, 0.f, 0.f, 0.f};
#pragma unroll
  for (int ks = 0; ks < 4; ++ks) {
#pragma unroll
    for (int t = 0; t < 8; ++t) {
      U4 bh, bl;
      const int off = ((ks * 8 + t) * 64 + lane) * 4;
      bh.i4 = *(const int4*)&s1[off];
      bl.i4 = *(const int4*)&s1[8192 + off];
      acc1[t] = __builtin_amdgcn_mfma_f32_16x16x32_bf16(ah[ks].v, bh.v, acc1[t], 0, 0, 0);
      acc1[t] = __builtin_amdgcn_mfma_f32_16x16x32_bf16(al[ks].v, bh.v, acc1[t], 0, 0, 0);
      acc1[t] = __builtin_amdgcn_mfma_f32_16x16x32_bf16(ah[ks].v, bl.v, acc1[t], 0, 0, 0);
    }
  }

  // ---- P2: +x, relu, pack single bf16 into wave-private LDS (stride 136) --
  unsigned short* __restrict__ h16 = (unsigned short*)h1w;
#pragma unroll
  for (int rr = 0; rr < 4; ++rr) {
    int row = row0 + 4 * lhi + rr;
    if (row >= n) row = n - 1;
    const float* __restrict__ xr = X + (size_t)row * DD;
#pragma unroll
    for (int t = 0; t < 8; ++t) {
      float v = acc1[t][rr] + xr[16 * t + l15];
      v = fmaxf(v, 0.f);
      h16[(4 * lhi + rr) * 136 + 16 * t + l15] = (unsigned short)bf16_rne(v);
    }
  }

  // ---- P3: z = H1a @ Wi2 (single bf16) ----
  f32x4 acc3[4];
#pragma unroll
  for (int t = 0; t < 4; ++t) acc3[t] = (f32x4){0.f, 0.f, 0.f, 0.f};
#pragma unroll
  for (int ks = 0; ks < 4; ++ks) {
    U4 a3;
    a3.i4 = *(const int4*)&h1w[l15 * 68 + ks * 16 + lhi * 4];
#pragma unroll
    for (int t = 0; t < 4; ++t) {
      U4 b3;
      b3.i4 = *(const int4*)&s2[((ks * 4 + t) * 64 + lane) * 4];
      acc3[t] = __builtin_amdgcn_mfma_f32_16x16x32_bf16(a3.v, b3.v, acc3[t], 0, 0, 0);
    }
  }

  // ---- P4: row softmax (64 cols = 4 tiles x 16 lanes) ----
#pragma unroll
  for (int rr = 0; rr < 4; ++rr) {
    const int row = row0 + 4 * lhi + rr;
    float z0 = acc3[0][rr], z1 = acc3[1][rr], z2 = acc3[2][rr], z3 = acc3[3][rr];
    float m = fmaxf(fmaxf(z0, z1), fmaxf(z2, z3));
#pragma unroll
    for (int off = 8; off >= 1; off >>= 1) m = fmaxf(m, __shfl_xor(m, off));
    const float p0 = expf(z0 - m), p1 = expf(z1 - m);
    const float p2 = expf(z2 - m), p3 = expf(z3 - m);
    float s = p0 + p1 + p2 + p3;
#pragma unroll
    for (int off = 8; off >= 1; off >>= 1) s += __shfl_xor(s, off);
    const float inv = 1.0f / s;
    if (row < n) {
      float* __restrict__ hr = H1g + (size_t)row * KK;
      hr[l15] = p0 * inv;
      hr[16 + l15] = p1 * inv;
      hr[32 + l15] = p2 * inv;
      hr[48 + l15] = p3 * inv;
      if (l15 == 0) {
        const float a = adj[row];
        trow[row] = a / (a + 1e-8f);
      }
    }
  }
}

// ---------------- per-block partial of M = (H1*t)^T @ X --------------------
__global__ __launch_bounds__(1024, 4) void k_c2(const float* __restrict__ X,
                                                const float* __restrict__ trow,
                                                const float* __restrict__ H1g,
                                                float* __restrict__ Mpart, int n) {
  __shared__ float cmb[3 * 4 * 16 * 2 * 64];  // 96 KB
  const int t = threadIdx.x;
  const int wave = t >> 6, lane = t & 63;
  const int rg = wave >> 2, kg = wave & 3;
  const int kb = kg * 16;
  const int d0 = 2 * lane;
  float macc[16][2];
#pragma unroll
  for (int j = 0; j < 16; ++j) { macc[j][0] = 0.f; macc[j][1] = 0.f; }
  const int bx = blockIdx.x;
  for (long row = (long)bx + 512L * rg; row < n; row += 2048L) {
    const int r = __builtin_amdgcn_readfirstlane((int)row);
    const float tr = trow[r];                         // s_load
    const float2 xv = *(const float2*)&X[(size_t)r * DD + d0];
    const float px0 = tr * xv.x, px1 = tr * xv.y;
    const float* __restrict__ hrow = H1g + (size_t)r * KK + kb;  // s_loads
#pragma unroll
    for (int j = 0; j < 16; ++j) {
      const float hj = hrow[j];
      macc[j][0] = fmaf(hj, px0, macc[j][0]);
      macc[j][1] = fmaf(hj, px1, macc[j][1]);
    }
  }
  if (rg > 0) {
    float* __restrict__ dst = cmb + ((rg - 1) * 4 + kg) * (16 * 2 * 64);
#pragma unroll
    for (int j = 0; j < 16; ++j) {
      dst[(2 * j + 0) * 64 + lane] = macc[j][0];
      dst[(2 * j + 1) * 64 + lane] = macc[j][1];
    }
  }
  __syncthreads();
  if (rg == 0) {
#pragma unroll
    for (int g = 0; g < 3; ++g) {
      const float* __restrict__ src = cmb + (g * 4 + kg) * (16 * 2 * 64);
#pragma unroll
      for (int j = 0; j < 16; ++j) {
        macc[j][0] += src[(2 * j + 0) * 64 + lane];
        macc[j][1] += src[(2 * j + 1) * 64 + lane];
      }
    }
    float* __restrict__ mp = Mpart + (size_t)bx * (KK * DD);
#pragma unroll
    for (int j = 0; j < 16; ++j)
      *(float2*)&mp[(kb + j) * DD + d0] = make_float2(macc[j][0], macc[j][1]);
  }
}

// ---------------- stage-1 fixed-order reduction of M partials --------------
__global__ void k_dred1(const float* __restrict__ Mpart, float* __restrict__ Mp2) {
  const int j = blockIdx.x * blockDim.x + threadIdx.x;  // 262144 threads
  const int i = j & (KK * DD - 1);
  const int c = j >> 13;
  float s = 0.f;
#pragma unroll
  for (int q = 0; q < 16; ++q)
    s += Mpart[(size_t)(c * 16 + q) * (KK * DD) + i];
  Mp2[(size_t)c * (KK * DD) + i] = s;
}

// ---- stage-2 reduction fused with frag prep: Mp2 -> split-bf16 M frags ----
__global__ void k_dred2p(const float* __restrict__ Mp2, unsigned* __restrict__ Mhi,
                         unsigned* __restrict__ Mlo) {
  const int id = blockIdx.x * 256 + threadIdx.x;  // 4096
  const int j = id & 3, l = (id >> 2) & 63, t = (id >> 8) & 7, ks = id >> 11;
  const int k0 = 32 * ks + 8 * (l >> 4) + 2 * j;
  const int col = 16 * t + (l & 15);
  float s0 = 0.f, s1 = 0.f;
#pragma unroll
  for (int c = 0; c < 32; ++c) {
    s0 += Mp2[(size_t)c * (KK * DD) + k0 * DD + col];
    s1 += Mp2[(size_t)c * (KK * DD) + (k0 + 1) * DD + col];
  }
  unsigned hi, lo;
  split2(s0, s1, hi, lo);
  Mhi[id] = hi;
  Mlo[id] = lo;
}

// ------- h = H1 @ M (split-bf16 MFMA); x = h + x; l2-normed outputs --------
__global__ __launch_bounds__(512) void k_fin_mfma(const float* __restrict__ H1g,
                                                  const unsigned* __restrict__ Mhi,
                                                  const unsigned* __restrict__ Mlo,
                                                  const float* __restrict__ emb,
                                                  float* __restrict__ Xb,
                                                  float* __restrict__ out,
                                                  int n, int first, int last) {
  __shared__ unsigned sm[2 * 4096];  // M frags hi|lo, 32 KB
  {
    const int t = threadIdx.x;
    uint4* d0 = (uint4*)sm;
    const uint4* s0 = (const uint4*)Mhi;
#pragma unroll
    for (int i = 0; i < 2; ++i) d0[t + 512 * i] = s0[t + 512 * i];
    uint4* d1 = (uint4*)(sm + 4096);
    const uint4* s1 = (const uint4*)Mlo;
#pragma unroll
    for (int i = 0; i < 2; ++i) d1[t + 512 * i] = s1[t + 512 * i];
  }
  __syncthreads();
  const int wave = threadIdx.x >> 6, lane = threadIdx.x & 63;
  const int l15 = lane & 15, lhi = lane >> 4;
  const size_t hoff = (size_t)n * DD;
  const int row0 = blockIdx.x * 128 + wave * 16;
  if (row0 >= n) return;

  // A frags: 16 H1 rows, K=64, split hi/lo
  U4 ah[2], al[2];
  {
    int ra = row0 + l15;
    if (ra >= n) ra = n - 1;
    const float* __restrict__ hp = H1g + (size_t)ra * KK;
#pragma unroll
    for (int ks = 0; ks < 2; ++ks) {
      const float4 x0 = *(const float4*)&hp[ks * 32 + lhi * 8];
      const float4 x1 = *(const float4*)&hp[ks * 32 + lhi * 8 + 4];
      split2(x0.x, x0.y, ah[ks].u[0], al[ks].u[0]);
      split2(x0.z, x0.w, ah[ks].u[1], al[ks].u[1]);
      split2(x1.x, x1.y, ah[ks].u[2], al[ks].u[2]);
      split2(x1.z, x1.w, ah[ks].u[3], al[ks].u[3]);
    }
  }
  f32x4 acc[8];
#pragma unroll
  for (int t = 0; t < 8; ++t) acc[t] = (f32x4){0.f, 0.f, 0.f, 0.f};
#pragma unroll
  for (int ks = 0; ks < 2; ++ks) {
#pragma unroll
    for (int t = 0; t < 8; ++t) {
      U4 bh, bl;
      const int off = ((ks * 8 + t) * 64 + lane) * 4;
      bh.i4 = *(const int4*)&sm[off];
      bl.i4 = *(const int4*)&sm[4096 + off];
      acc[t] = __builtin_amdgcn_mfma_f32_16x16x32_bf16(ah[ks].v, bh.v, acc[t], 0, 0, 0);
      acc[t] = __builtin_amdgcn_mfma_f32_16x16x32_bf16(al[ks].v, bh.v, acc[t], 0, 0, 0);
      acc[t] = __builtin_amdgcn_mfma_f32_16x16x32_bf16(ah[ks].v, bl.v, acc[t], 0, 0, 0);
    }
  }
  // epilogue: per row (4 per lhi-group), cols 16t+l15
#pragma unroll
  for (int rr = 0; rr < 4; ++rr) {
    const int row = row0 + 4 * lhi + rr;
    const int rc = (row < n) ? row : (n - 1);
    float hh[8], xx[8];
    float sh = 0.f, sx = 0.f;
#pragma unroll
    for (int t = 0; t < 8; ++t) {
      const float xv = Xb[(size_t)rc * DD + 16 * t + l15];
      hh[t] = acc[t][rr];
      xx[t] = hh[t] + xv;
      sh = fmaf(hh[t], hh[t], sh);
      sx = fmaf(xx[t], xx[t], sx);
    }
#pragma unroll
    for (int off = 8; off >= 1; off >>= 1) {  // reduce within 16-lane row group
      sh += __shfl_xor(sh, off);
      sx += __shfl_xor(sx, off);
    }
    const float ih = 0.5f / fmaxf(sqrtf(sh), 1e-12f);
    const float ix = (1.0f / 3.0f) / fmaxf(sqrtf(sx), 1e-12f);
    if (row < n) {
#pragma unroll
      for (int t = 0; t < 8; ++t) {
        const size_t oi = (size_t)row * DD + 16 * t + l15;
        if (!last) Xb[oi] = xx[t];   // xb dead after last layer
        float ci, ch;
        if (first) {
          ci = emb[oi] * (1.0f / 3.0f);
          ch = 0.f;
        } else {
          ci = out[oi];
          ch = out[hoff + oi];
        }
        out[oi] = ci + xx[t] * ix;
        out[hoff + oi] = ch + hh[t] * ih;
      }
    }
  }
}

extern "C" void kernel_launch(void* const* d_in, const int* in_sizes, int n_in,
                              void* d_out, int out_size, void* d_ws, size_t ws_size,
                              hipStream_t stream) {
  const float* adj  = (const float*)d_in[0];
  const int*   erow = (const int*)d_in[1];
  const int*   ecol = (const int*)d_in[2];
  const float* eval = (const float*)d_in[3];
  const float* emb  = (const float*)d_in[4];
  const float* W0   = (const float*)d_in[5];
  const float* W1   = (const float*)d_in[6];
  const float* Wi1  = (const float*)d_in[7];
  const float* Wi2  = (const float*)d_in[8];
  const int n = in_sizes[0];
  const int E = in_sizes[1];
  float* out = (float*)d_out;

  float* xb    = (float*)d_ws;
  float* yb    = xb + (size_t)n * DD;
  unsigned short* Ybf = (unsigned short*)yb;
  float* H1g   = yb + (size_t)n * (DD / 2);  // after Ybf region (Ybf dead by c1)
  float* Mpart = H1g + (size_t)n * KK;
  float* Mp2   = Mpart + (size_t)NBLK_C2 * KK * DD;
  float* Mg    = Mp2 + (size_t)32 * KK * DD;  // (unused; layout keeper)
  int*   cnt    = (int*)(Mg + KK * DD);
  int*   rowptr = cnt + n;
  int*   csum   = rowptr + n + 4;
  int*   coff   = csum + 256;
  int2*  erec   = (int2*)(coff + 256);
  float* trow   = (float*)(erec + E);
  unsigned* w0hi  = (unsigned*)(trow + n);
  unsigned* w0lo  = w0hi + 8192;
  unsigned* w1hi_ = w0lo + 8192;
  unsigned* w1lo_ = w1hi_ + 8192;
  unsigned* wi1hi = w1lo_ + 8192;
  unsigned* wi1lo = wi1hi + 8192;
  unsigned* wi2f  = wi1lo + 8192;
  unsigned* mhi   = wi2f + 4096;
  unsigned* mlo   = mhi + 4096;

  const int NCH = (n + CH - 1) / CH;

  // ---- weight prep (once per launch) ----
  k_prepW<<<32, 256, 0, stream>>>(W0, w0hi, w0lo);
  k_prepW<<<32, 256, 0, stream>>>(W1, w1hi_, w1lo_);
  k_prepW<<<32, 256, 0, stream>>>(Wi1, wi1hi, wi1lo);
  k_prepWs<<<16, 256, 0, stream>>>(Wi2, wi2f);

  // ---- CSR build (once per launch; deterministic work) ----
  hipMemsetAsync(cnt, 0, (size_t)n * sizeof(int), stream);
  k_hist<<<2048, 256, 0, stream>>>(erow, cnt, E);
  k_chunksum<<<NCH, 256, 0, stream>>>(cnt, csum, n);
  k_chunkscan<<<1, 256, 0, stream>>>(csum, coff, NCH);
  k_rowptr<<<NCH, 256, 0, stream>>>(cnt, coff, rowptr, n, E);
  hipMemsetAsync(cnt, 0, (size_t)n * sizeof(int), stream);
  k_scatter<<<2048, 256, 0, stream>>>(erow, ecol, eval, rowptr, cnt, erec, E);

  const int g_gm  = (n + 255) / 256;   // 8 waves x 32 rows
  const int g_c1m = (n + 127) / 128;   // 8 waves x 16 rows
  const int g_fin = (n + 127) / 128;   // 8 waves x 16 rows

  for (int L = 0; L < 2; ++L) {
    const unsigned* Whi = (L == 0) ? w0hi : w1hi_;
    const unsigned* Wlo = (L == 0) ? w0lo : w1lo_;
    const float* Xin = (L == 0) ? emb : xb;
    k_gemm_mfma<<<g_gm, 512, 0, stream>>>(Xin, Whi, Wlo, Ybf, n);
    k_spmm_csr<<<2048, 256, 0, stream>>>(rowptr, erec, (const unsigned*)Ybf, xb, n);
    k_c1_mfma<<<g_c1m, 512, 0, stream>>>(xb, wi1hi, wi1lo, wi2f, adj, H1g, trow, n);
    k_c2<<<NBLK_C2, 1024, 0, stream>>>(xb, trow, H1g, Mpart, n);
    k_dred1<<<1024, 256, 0, stream>>>(Mpart, Mp2);
    k_dred2p<<<16, 256, 0, stream>>>(Mp2, mhi, mlo);
    k_fin_mfma<<<g_fin, 512, 0, stream>>>(H1g, mhi, mlo, emb, xb, out, n,
                                          (L == 0) ? 1 : 0, (L == 1) ? 1 : 0);
  }
}

// Round 15
// 646.464 us; speedup vs baseline: 1.1502x; 1.0691x over previous
//
#include <hip/hip_runtime.h>

constexpr int DD = 128;   // emb size
constexpr int KK = 64;    // clusters
constexpr int NBLK_C2 = 512;
constexpr int CH = 512;   // rows per scan chunk

typedef __attribute__((ext_vector_type(8))) short bf16x8;
typedef __attribute__((ext_vector_type(4))) float f32x4;

union U4 { unsigned u[4]; int4 i4; bf16x8 v; };

__device__ inline unsigned bf16_rne(float x) {
  unsigned u = __float_as_uint(x);
  u += 0x7fff + ((u >> 16) & 1);
  return u >> 16;
}
__device__ inline float bf16f(unsigned h) { return __uint_as_float(h << 16); }
__device__ inline void split2(float a, float b, unsigned& hi, unsigned& lo) {
  const unsigned h0 = bf16_rne(a), h1 = bf16_rne(b);
  const unsigned l0 = bf16_rne(a - bf16f(h0)), l1 = bf16_rne(b - bf16f(h1));
  hi = h0 | (h1 << 16);
  lo = l0 | (l1 << 16);
}

// ---- weight prep: frag-ordered split bf16. out idx = ((ks*nt+t)*64+l)*4+j ---
__global__ void k_prepW(const float* __restrict__ W, unsigned* __restrict__ Whi,
                        unsigned* __restrict__ Wlo) {  // 128x128, nt=8
  const int id = blockIdx.x * 256 + threadIdx.x;  // 8192
  const int j = id & 3, l = (id >> 2) & 63, t = (id >> 8) & 7, ks = id >> 11;
  const int k0 = 32 * ks + 8 * (l >> 4) + 2 * j;
  const int col = 16 * t + (l & 15);
  const float e0 = W[k0 * 128 + col], e1 = W[(k0 + 1) * 128 + col];
  unsigned hi, lo;
  split2(e0, e1, hi, lo);
  Whi[id] = hi;
  Wlo[id] = lo;
}

__global__ void k_prepWs(const float* __restrict__ W, unsigned* __restrict__ Wf) {
  const int id = blockIdx.x * 256 + threadIdx.x;  // 4096 (128x64, nt=4)
  const int j = id & 3, l = (id >> 2) & 63, t = (id >> 8) & 3, ks = id >> 10;
  const int k0 = 32 * ks + 8 * (l >> 4) + 2 * j;
  const int col = 16 * t + (l & 15);
  const unsigned h0 = bf16_rne(W[k0 * 64 + col]);
  const unsigned h1 = bf16_rne(W[(k0 + 1) * 64 + col]);
  Wf[id] = h0 | (h1 << 16);
}

// ---------------- Y(bf16) = X @ W via MFMA bf16x3 split ---------------------
__global__ __launch_bounds__(512) void k_gemm_mfma(const float* __restrict__ X,
                                                   const unsigned* __restrict__ Whi,
                                                   const unsigned* __restrict__ Wlo,
                                                   unsigned short* __restrict__ Yb,
                                                   int n) {
  __shared__ unsigned sb[2 * 8192];  // hi | lo, 64 KB
  {
    const int t = threadIdx.x;
    uint4* d0 = (uint4*)sb;
    const uint4* s0 = (const uint4*)Whi;
#pragma unroll
    for (int i = 0; i < 4; ++i) d0[t + 512 * i] = s0[t + 512 * i];
    uint4* d1 = (uint4*)(sb + 8192);
    const uint4* s1 = (const uint4*)Wlo;
#pragma unroll
    for (int i = 0; i < 4; ++i) d1[t + 512 * i] = s1[t + 512 * i];
  }
  __syncthreads();
  const int wave = threadIdx.x >> 6, lane = threadIdx.x & 63;
  const int l15 = lane & 15, lhi = lane >> 4;
  const int row0 = blockIdx.x * 256 + wave * 32;
  if (row0 >= n) return;
  f32x4 acc[2][8];
#pragma unroll
  for (int rt = 0; rt < 2; ++rt)
#pragma unroll
    for (int t = 0; t < 8; ++t) acc[rt][t] = (f32x4){0.f, 0.f, 0.f, 0.f};
#pragma unroll
  for (int ks = 0; ks < 4; ++ks) {
    U4 ah[2], al[2];
#pragma unroll
    for (int rt = 0; rt < 2; ++rt) {
      int r = row0 + rt * 16 + l15;
      if (r >= n) r = n - 1;
      const float4 x0 = *(const float4*)&X[(size_t)r * DD + ks * 32 + lhi * 8];
      const float4 x1 = *(const float4*)&X[(size_t)r * DD + ks * 32 + lhi * 8 + 4];
      split2(x0.x, x0.y, ah[rt].u[0], al[rt].u[0]);
      split2(x0.z, x0.w, ah[rt].u[1], al[rt].u[1]);
      split2(x1.x, x1.y, ah[rt].u[2], al[rt].u[2]);
      split2(x1.z, x1.w, ah[rt].u[3], al[rt].u[3]);
    }
#pragma unroll
    for (int t = 0; t < 8; ++t) {
      U4 bh, bl;
      const int off = ((ks * 8 + t) * 64 + lane) * 4;
      bh.i4 = *(const int4*)&sb[off];
      bl.i4 = *(const int4*)&sb[8192 + off];
#pragma unroll
      for (int rt = 0; rt < 2; ++rt) {
        acc[rt][t] = __builtin_amdgcn_mfma_f32_16x16x32_bf16(ah[rt].v, bh.v, acc[rt][t], 0, 0, 0);
        acc[rt][t] = __builtin_amdgcn_mfma_f32_16x16x32_bf16(al[rt].v, bh.v, acc[rt][t], 0, 0, 0);
        acc[rt][t] = __builtin_amdgcn_mfma_f32_16x16x32_bf16(ah[rt].v, bl.v, acc[rt][t], 0, 0, 0);
      }
    }
  }
#pragma unroll
  for (int rt = 0; rt < 2; ++rt)
#pragma unroll
    for (int rr = 0; rr < 4; ++rr) {
      const int row = row0 + rt * 16 + lhi * 4 + rr;
      if (row < n) {
#pragma unroll
        for (int t = 0; t < 8; ++t)
          Yb[(size_t)row * DD + t * 16 + l15] =
              (unsigned short)bf16_rne(acc[rt][t][rr]);
      }
    }
}

// ---------------- CSR build: rank-hist -> scan -> atomic-free place --------
// rank[e] = within-row arrival index (single atomic pass, result reused).
__global__ void k_hist2(const int* __restrict__ er, int* __restrict__ cnt,
                        int* __restrict__ rank, int E) {
  for (long e = (long)blockIdx.x * blockDim.x + threadIdx.x; e < E;
       e += (long)gridDim.x * blockDim.x)
    rank[e] = atomicAdd(&cnt[er[e]], 1);
}

__global__ __launch_bounds__(256) void k_chunksum(const int* __restrict__ cnt,
                                                  int* __restrict__ csum, int n) {
  const int c = blockIdx.x, t = threadIdx.x;
  const int i0 = c * CH + 2 * t;
  int s2 = 0;
  if (i0 < n) s2 += cnt[i0];
  if (i0 + 1 < n) s2 += cnt[i0 + 1];
#pragma unroll
  for (int off = 32; off >= 1; off >>= 1) s2 += __shfl_xor(s2, off);
  __shared__ int ws_[4];
  if ((t & 63) == 0) ws_[t >> 6] = s2;
  __syncthreads();
  if (t == 0) csum[c] = ws_[0] + ws_[1] + ws_[2] + ws_[3];
}

__global__ __launch_bounds__(256) void k_chunkscan(const int* __restrict__ csum,
                                                   int* __restrict__ coff, int nch) {
  __shared__ int s[256];
  const int t = threadIdx.x;
  const int v = (t < nch) ? csum[t] : 0;
  s[t] = v;
  __syncthreads();
  for (int off = 1; off < 256; off <<= 1) {
    const int u = (t >= off) ? s[t - off] : 0;
    __syncthreads();
    s[t] += u;
    __syncthreads();
  }
  coff[t] = s[t] - v;   // exclusive
}

__global__ __launch_bounds__(256) void k_rowptr(const int* __restrict__ cnt,
                                                const int* __restrict__ coff,
                                                int* __restrict__ rowptr,
                                                int n, int E) {
  const int c = blockIdx.x, t = threadIdx.x;
  const int i0 = c * CH + 2 * t, i1 = i0 + 1;
  const int v0 = (i0 < n) ? cnt[i0] : 0;
  const int v1 = (i1 < n) ? cnt[i1] : 0;
  __shared__ int s[256];
  const int s2 = v0 + v1;
  s[t] = s2;
  __syncthreads();
  for (int off = 1; off < 256; off <<= 1) {
    const int u = (t >= off) ? s[t - off] : 0;
    __syncthreads();
    s[t] += u;
    __syncthreads();
  }
  const int excl = s[t] - s2 + coff[c];
  if (i0 < n) rowptr[i0] = excl;
  if (i1 < n) rowptr[i1] = excl + v0;
  if (c == 0 && t == 0) rowptr[n] = E;
}

// place: erec[rowptr[r] + rank[e]] = {col, val}. No atomics, max MLP.
__global__ void k_place(const int* __restrict__ er, const int* __restrict__ ec,
                        const float* __restrict__ ev, const int* __restrict__ rank,
                        const int* __restrict__ rowptr, int2* __restrict__ erec,
                        int E) {
  for (long e = (long)blockIdx.x * blockDim.x + threadIdx.x; e < E;
       e += (long)gridDim.x * blockDim.x) {
    const int r = er[e];
    erec[rowptr[r] + rank[e]] = make_int2(ec[e], __float_as_int(ev[e]));
  }
}

// ---------------- SPMM (CSR): one wave per row, bf16 gather, 4x MLP -------
__global__ __launch_bounds__(256) void k_spmm_csr(const int* __restrict__ rowptr,
                                                  const int2* __restrict__ erec,
                                                  const unsigned* __restrict__ Yb,
                                                  float* __restrict__ Xo, int n) {
  const int lane = threadIdx.x & 63;
  const int c0 = 2 * lane;
  const long gw = (long)blockIdx.x * 4 + (threadIdx.x >> 6);
  const long nw = (long)gridDim.x * 4;
  for (long row = gw; row < n; row += nw) {
    const int b = rowptr[row], e2 = rowptr[row + 1];  // uniform -> s_load
    float a0 = 0.f, a1 = 0.f, b0 = 0.f, b1 = 0.f;
    float c00 = 0.f, c1 = 0.f, d0 = 0.f, d1 = 0.f;
    int e = b;
    for (; e + 4 <= e2; e += 4) {  // 4 independent gathers in flight
      const int2 r0 = erec[e], r1 = erec[e + 1];
      const int2 r2 = erec[e + 2], r3 = erec[e + 3];  // 32B uniform s_load
      const unsigned q0 = Yb[(size_t)r0.x * (DD / 2) + lane];
      const unsigned q1 = Yb[(size_t)r1.x * (DD / 2) + lane];
      const unsigned q2 = Yb[(size_t)r2.x * (DD / 2) + lane];
      const unsigned q3 = Yb[(size_t)r3.x * (DD / 2) + lane];
      const float v0 = __int_as_float(r0.y), v1 = __int_as_float(r1.y);
      const float v2 = __int_as_float(r2.y), v3 = __int_as_float(r3.y);
      a0 = fmaf(v0, __uint_as_float(q0 << 16), a0);
      a1 = fmaf(v0, __uint_as_float(q0 & 0xffff0000u), a1);
      b0 = fmaf(v1, __uint_as_float(q1 << 16), b0);
      b1 = fmaf(v1, __uint_as_float(q1 & 0xffff0000u), b1);
      c00 = fmaf(v2, __uint_as_float(q2 << 16), c00);
      c1 = fmaf(v2, __uint_as_float(q2 & 0xffff0000u), c1);
      d0 = fmaf(v3, __uint_as_float(q3 << 16), d0);
      d1 = fmaf(v3, __uint_as_float(q3 & 0xffff0000u), d1);
    }
    for (; e + 2 <= e2; e += 2) {
      const int2 r0 = erec[e], r1 = erec[e + 1];
      const float v0 = __int_as_float(r0.y), v1 = __int_as_float(r1.y);
      const unsigned q0 = Yb[(size_t)r0.x * (DD / 2) + lane];
      const unsigned q1 = Yb[(size_t)r1.x * (DD / 2) + lane];
      a0 = fmaf(v0, __uint_as_float(q0 << 16), a0);
      a1 = fmaf(v0, __uint_as_float(q0 & 0xffff0000u), a1);
      b0 = fmaf(v1, __uint_as_float(q1 << 16), b0);
      b1 = fmaf(v1, __uint_as_float(q1 & 0xffff0000u), b1);
    }
    if (e < e2) {
      const int2 r0 = erec[e];
      const float v = __int_as_float(r0.y);
      const unsigned q = Yb[(size_t)r0.x * (DD / 2) + lane];
      a0 = fmaf(v, __uint_as_float(q << 16), a0);
      a1 = fmaf(v, __uint_as_float(q & 0xffff0000u), a1);
    }
    *(float2*)&Xo[(size_t)row * DD + c0] =
        make_float2((a0 + b0) + (c00 + d0), (a1 + b1) + (c1 + d1));
  }
}

// ---------------- fused: H1 = softmax(relu(X@Wi1 + X) @ Wi2), MFMA --------
__global__ __launch_bounds__(512) void k_c1_mfma(const float* __restrict__ X,
                                                 const unsigned* __restrict__ W1hi,
                                                 const unsigned* __restrict__ W1lo,
                                                 const unsigned* __restrict__ W2f,
                                                 const float* __restrict__ adj,
                                                 float* __restrict__ H1g,
                                                 float* __restrict__ trow, int n) {
  __shared__ unsigned s1[2 * 8192];     // Wi1 frags hi|lo, 64 KB
  __shared__ unsigned s2[4096];         // Wi2 frags, 16 KB
  __shared__ unsigned h1s[8 * 16 * 68]; // 8 waves x (16 rows x 68 u32), 34 KB
  {
    const int t = threadIdx.x;
    uint4* d0 = (uint4*)s1;
    const uint4* sA = (const uint4*)W1hi;
    const uint4* sB = (const uint4*)W1lo;
#pragma unroll
    for (int i = 0; i < 4; ++i) d0[t + 512 * i] = sA[t + 512 * i];
    uint4* d1 = (uint4*)(s1 + 8192);
#pragma unroll
    for (int i = 0; i < 4; ++i) d1[t + 512 * i] = sB[t + 512 * i];
    uint4* d2 = (uint4*)s2;
    const uint4* sC = (const uint4*)W2f;
#pragma unroll
    for (int i = 0; i < 2; ++i) d2[t + 512 * i] = sC[t + 512 * i];
  }
  __syncthreads();
  const int wave = threadIdx.x >> 6, lane = threadIdx.x & 63;
  const int l15 = lane & 15, lhi = lane >> 4;
  unsigned* __restrict__ h1w = h1s + wave * (16 * 68);
  const int row0 = blockIdx.x * 128 + wave * 16;
  if (row0 >= n) return;

  // ---- P1: acc1 = x @ Wi1 (split bf16, 3 MFMA) ----
  U4 ah[4], al[4];
#pragma unroll
  for (int ks = 0; ks < 4; ++ks) {
    int r = row0 + l15;
    if (r >= n) r = n - 1;
    const float4 x0 = *(const float4*)&X[(size_t)r * DD + ks * 32 + lhi * 8];
    const float4 x1 = *(const float4*)&X[(size_t)r * DD + ks * 32 + lhi * 8 + 4];
    split2(x0.x, x0.y, ah[ks].u[0], al[ks].u[0]);
    split2(x0.z, x0.w, ah[ks].u[1], al[ks].u[1]);
    split2(x1.x, x1.y, ah[ks].u[2], al[ks].u[2]);
    split2(x1.z, x1.w, ah[ks].u[3], al[ks].u[3]);
  }
  f32x4 acc1[8];
#pragma unroll
  for (int t = 0; t < 8; ++t) acc1[t] = (f32x4){0.f, 0.f, 0.f, 0.f};
#pragma unroll
  for (int ks = 0; ks < 4; ++ks) {
#pragma unroll
    for (int t = 0; t < 8; ++t) {
      U4 bh, bl;
      const int off = ((ks * 8 + t) * 64 + lane) * 4;
      bh.i4 = *(const int4*)&s1[off];
      bl.i4 = *(const int4*)&s1[8192 + off];
      acc1[t] = __builtin_amdgcn_mfma_f32_16x16x32_bf16(ah[ks].v, bh.v, acc1[t], 0, 0, 0);
      acc1[t] = __builtin_amdgcn_mfma_f32_16x16x32_bf16(al[ks].v, bh.v, acc1[t], 0, 0, 0);
      acc1[t] = __builtin_amdgcn_mfma_f32_16x16x32_bf16(ah[ks].v, bl.v, acc1[t], 0, 0, 0);
    }
  }

  // ---- P2: +x, relu, pack single bf16 into wave-private LDS (stride 136) --
  unsigned short* __restrict__ h16 = (unsigned short*)h1w;
#pragma unroll
  for (int rr = 0; rr < 4; ++rr) {
    int row = row0 + 4 * lhi + rr;
    if (row >= n) row = n - 1;
    const float* __restrict__ xr = X + (size_t)row * DD;
#pragma unroll
    for (int t = 0; t < 8; ++t) {
      float v = acc1[t][rr] + xr[16 * t + l15];
      v = fmaxf(v, 0.f);
      h16[(4 * lhi + rr) * 136 + 16 * t + l15] = (unsigned short)bf16_rne(v);
    }
  }

  // ---- P3: z = H1a @ Wi2 (single bf16) ----
  f32x4 acc3[4];
#pragma unroll
  for (int t = 0; t < 4; ++t) acc3[t] = (f32x4){0.f, 0.f, 0.f, 0.f};
#pragma unroll
  for (int ks = 0; ks < 4; ++ks) {
    U4 a3;
    a3.i4 = *(const int4*)&h1w[l15 * 68 + ks * 16 + lhi * 4];
#pragma unroll
    for (int t = 0; t < 4; ++t) {
      U4 b3;
      b3.i4 = *(const int4*)&s2[((ks * 4 + t) * 64 + lane) * 4];
      acc3[t] = __builtin_amdgcn_mfma_f32_16x16x32_bf16(a3.v, b3.v, acc3[t], 0, 0, 0);
    }
  }

  // ---- P4: row softmax (64 cols = 4 tiles x 16 lanes) ----
#pragma unroll
  for (int rr = 0; rr < 4; ++rr) {
    const int row = row0 + 4 * lhi + rr;
    float z0 = acc3[0][rr], z1 = acc3[1][rr], z2 = acc3[2][rr], z3 = acc3[3][rr];
    float m = fmaxf(fmaxf(z0, z1), fmaxf(z2, z3));
#pragma unroll
    for (int off = 8; off >= 1; off >>= 1) m = fmaxf(m, __shfl_xor(m, off));
    const float p0 = expf(z0 - m), p1 = expf(z1 - m);
    const float p2 = expf(z2 - m), p3 = expf(z3 - m);
    float s = p0 + p1 + p2 + p3;
#pragma unroll
    for (int off = 8; off >= 1; off >>= 1) s += __shfl_xor(s, off);
    const float inv = 1.0f / s;
    if (row < n) {
      float* __restrict__ hr = H1g + (size_t)row * KK;
      hr[l15] = p0 * inv;
      hr[16 + l15] = p1 * inv;
      hr[32 + l15] = p2 * inv;
      hr[48 + l15] = p3 * inv;
      if (l15 == 0) {
        const float a = adj[row];
        trow[row] = a / (a + 1e-8f);
      }
    }
  }
}

// ---------------- per-block partial of M = (H1*t)^T @ X --------------------
__global__ __launch_bounds__(1024, 4) void k_c2(const float* __restrict__ X,
                                                const float* __restrict__ trow,
                                                const float* __restrict__ H1g,
                                                float* __restrict__ Mpart, int n) {
  __shared__ float cmb[3 * 4 * 16 * 2 * 64];  // 96 KB
  const int t = threadIdx.x;
  const int wave = t >> 6, lane = t & 63;
  const int rg = wave >> 2, kg = wave & 3;
  const int kb = kg * 16;
  const int d0 = 2 * lane;
  float macc[16][2];
#pragma unroll
  for (int j = 0; j < 16; ++j) { macc[j][0] = 0.f; macc[j][1] = 0.f; }
  const int bx = blockIdx.x;
  for (long row = (long)bx + 512L * rg; row < n; row += 2048L) {
    const int r = __builtin_amdgcn_readfirstlane((int)row);
    const float tr = trow[r];                         // s_load
    const float2 xv = *(const float2*)&X[(size_t)r * DD + d0];
    const float px0 = tr * xv.x, px1 = tr * xv.y;
    const float* __restrict__ hrow = H1g + (size_t)r * KK + kb;  // s_loads
#pragma unroll
    for (int j = 0; j < 16; ++j) {
      const float hj = hrow[j];
      macc[j][0] = fmaf(hj, px0, macc[j][0]);
      macc[j][1] = fmaf(hj, px1, macc[j][1]);
    }
  }
  if (rg > 0) {
    float* __restrict__ dst = cmb + ((rg - 1) * 4 + kg) * (16 * 2 * 64);
#pragma unroll
    for (int j = 0; j < 16; ++j) {
      dst[(2 * j + 0) * 64 + lane] = macc[j][0];
      dst[(2 * j + 1) * 64 + lane] = macc[j][1];
    }
  }
  __syncthreads();
  if (rg == 0) {
#pragma unroll
    for (int g = 0; g < 3; ++g) {
      const float* __restrict__ src = cmb + (g * 4 + kg) * (16 * 2 * 64);
#pragma unroll
      for (int j = 0; j < 16; ++j) {
        macc[j][0] += src[(2 * j + 0) * 64 + lane];
        macc[j][1] += src[(2 * j + 1) * 64 + lane];
      }
    }
    float* __restrict__ mp = Mpart + (size_t)bx * (KK * DD);
#pragma unroll
    for (int j = 0; j < 16; ++j)
      *(float2*)&mp[(kb + j) * DD + d0] = make_float2(macc[j][0], macc[j][1]);
  }
}

// ---------------- stage-1 fixed-order reduction of M partials --------------
__global__ void k_dred1(const float* __restrict__ Mpart, float* __restrict__ Mp2) {
  const int j = blockIdx.x * blockDim.x + threadIdx.x;  // 262144 threads
  const int i = j & (KK * DD - 1);
  const int c = j >> 13;
  float s = 0.f;
#pragma unroll
  for (int q = 0; q < 16; ++q)
    s += Mpart[(size_t)(c * 16 + q) * (KK * DD) + i];
  Mp2[(size_t)c * (KK * DD) + i] = s;
}

// ---- stage-2 reduction fused with frag prep: Mp2 -> split-bf16 M frags ----
__global__ void k_dred2p(const float* __restrict__ Mp2, unsigned* __restrict__ Mhi,
                         unsigned* __restrict__ Mlo) {
  const int id = blockIdx.x * 256 + threadIdx.x;  // 4096
  const int j = id & 3, l = (id >> 2) & 63, t = (id >> 8) & 7, ks = id >> 11;
  const int k0 = 32 * ks + 8 * (l >> 4) + 2 * j;
  const int col = 16 * t + (l & 15);
  float s0 = 0.f, s1 = 0.f;
#pragma unroll
  for (int c = 0; c < 32; ++c) {
    s0 += Mp2[(size_t)c * (KK * DD) + k0 * DD + col];
    s1 += Mp2[(size_t)c * (KK * DD) + (k0 + 1) * DD + col];
  }
  unsigned hi, lo;
  split2(s0, s1, hi, lo);
  Mhi[id] = hi;
  Mlo[id] = lo;
}

// ------- h = H1 @ M (split-bf16 MFMA); x = h + x; l2-normed outputs --------
__global__ __launch_bounds__(512) void k_fin_mfma(const float* __restrict__ H1g,
                                                  const unsigned* __restrict__ Mhi,
                                                  const unsigned* __restrict__ Mlo,
                                                  const float* __restrict__ emb,
                                                  float* __restrict__ Xb,
                                                  float* __restrict__ out,
                                                  int n, int first, int last) {
  __shared__ unsigned sm[2 * 4096];  // M frags hi|lo, 32 KB
  {
    const int t = threadIdx.x;
    uint4* d0 = (uint4*)sm;
    const uint4* s0 = (const uint4*)Mhi;
#pragma unroll
    for (int i = 0; i < 2; ++i) d0[t + 512 * i] = s0[t + 512 * i];
    uint4* d1 = (uint4*)(sm + 4096);
    const uint4* s1 = (const uint4*)Mlo;
#pragma unroll
    for (int i = 0; i < 2; ++i) d1[t + 512 * i] = s1[t + 512 * i];
  }
  __syncthreads();
  const int wave = threadIdx.x >> 6, lane = threadIdx.x & 63;
  const int l15 = lane & 15, lhi = lane >> 4;
  const size_t hoff = (size_t)n * DD;
  const int row0 = blockIdx.x * 128 + wave * 16;
  if (row0 >= n) return;

  // A frags: 16 H1 rows, K=64, split hi/lo
  U4 ah[2], al[2];
  {
    int ra = row0 + l15;
    if (ra >= n) ra = n - 1;
    const float* __restrict__ hp = H1g + (size_t)ra * KK;
#pragma unroll
    for (int ks = 0; ks < 2; ++ks) {
      const float4 x0 = *(const float4*)&hp[ks * 32 + lhi * 8];
      const float4 x1 = *(const float4*)&hp[ks * 32 + lhi * 8 + 4];
      split2(x0.x, x0.y, ah[ks].u[0], al[ks].u[0]);
      split2(x0.z, x0.w, ah[ks].u[1], al[ks].u[1]);
      split2(x1.x, x1.y, ah[ks].u[2], al[ks].u[2]);
      split2(x1.z, x1.w, ah[ks].u[3], al[ks].u[3]);
    }
  }
  f32x4 acc[8];
#pragma unroll
  for (int t = 0; t < 8; ++t) acc[t] = (f32x4){0.f, 0.f, 0.f, 0.f};
#pragma unroll
  for (int ks = 0; ks < 2; ++ks) {
#pragma unroll
    for (int t = 0; t < 8; ++t) {
      U4 bh, bl;
      const int off = ((ks * 8 + t) * 64 + lane) * 4;
      bh.i4 = *(const int4*)&sm[off];
      bl.i4 = *(const int4*)&sm[4096 + off];
      acc[t] = __builtin_amdgcn_mfma_f32_16x16x32_bf16(ah[ks].v, bh.v, acc[t], 0, 0, 0);
      acc[t] = __builtin_amdgcn_mfma_f32_16x16x32_bf16(al[ks].v, bh.v, acc[t], 0, 0, 0);
      acc[t] = __builtin_amdgcn_mfma_f32_16x16x32_bf16(ah[ks].v, bl.v, acc[t], 0, 0, 0);
    }
  }
  // epilogue: per row (4 per lhi-group), cols 16t+l15
#pragma unroll
  for (int rr = 0; rr < 4; ++rr) {
    const int row = row0 + 4 * lhi + rr;
    const int rc = (row < n) ? row : (n - 1);
    float hh[8], xx[8];
    float sh = 0.f, sx = 0.f;
#pragma unroll
    for (int t = 0; t < 8; ++t) {
      const float xv = Xb[(size_t)rc * DD + 16 * t + l15];
      hh[t] = acc[t][rr];
      xx[t] = hh[t] + xv;
      sh = fmaf(hh[t], hh[t], sh);
      sx = fmaf(xx[t], xx[t], sx);
    }
#pragma unroll
    for (int off = 8; off >= 1; off >>= 1) {  // reduce within 16-lane row group
      sh += __shfl_xor(sh, off);
      sx += __shfl_xor(sx, off);
    }
    const float ih = 0.5f / fmaxf(sqrtf(sh), 1e-12f);
    const float ix = (1.0f / 3.0f) / fmaxf(sqrtf(sx), 1e-12f);
    if (row < n) {
#pragma unroll
      for (int t = 0; t < 8; ++t) {
        const size_t oi = (size_t)row * DD + 16 * t + l15;
        if (!last) Xb[oi] = xx[t];   // xb dead after last layer
        float ci, ch;
        if (first) {
          ci = emb[oi] * (1.0f / 3.0f);
          ch = 0.f;
        } else {
          ci = out[oi];
          ch = out[hoff + oi];
        }
        out[oi] = ci + xx[t] * ix;
        out[hoff + oi] = ch + hh[t] * ih;
      }
    }
  }
}

extern "C" void kernel_launch(void* const* d_in, const int* in_sizes, int n_in,
                              void* d_out, int out_size, void* d_ws, size_t ws_size,
                              hipStream_t stream) {
  const float* adj  = (const float*)d_in[0];
  const int*   erow = (const int*)d_in[1];
  const int*   ecol = (const int*)d_in[2];
  const float* eval = (const float*)d_in[3];
  const float* emb  = (const float*)d_in[4];
  const float* W0   = (const float*)d_in[5];
  const float* W1   = (const float*)d_in[6];
  const float* Wi1  = (const float*)d_in[7];
  const float* Wi2  = (const float*)d_in[8];
  const int n = in_sizes[0];
  const int E = in_sizes[1];
  float* out = (float*)d_out;

  float* xb    = (float*)d_ws;
  float* yb    = xb + (size_t)n * DD;
  unsigned short* Ybf = (unsigned short*)yb;
  float* H1g   = yb + (size_t)n * (DD / 2);  // after Ybf region (Ybf dead by c1)
  float* Mpart = H1g + (size_t)n * KK;
  float* Mp2   = Mpart + (size_t)NBLK_C2 * KK * DD;
  float* Mg    = Mp2 + (size_t)32 * KK * DD;  // (layout keeper)
  int*   cnt    = (int*)(Mg + KK * DD);
  int*   rowptr = cnt + n;
  int*   csum   = rowptr + n + 4;
  int*   coff   = csum + 256;
  int2*  erec   = (int2*)(coff + 256);
  float* trow   = (float*)(erec + E);
  unsigned* w0hi  = (unsigned*)(trow + n);
  unsigned* w0lo  = w0hi + 8192;
  unsigned* w1hi_ = w0lo + 8192;
  unsigned* w1lo_ = w1hi_ + 8192;
  unsigned* wi1hi = w1lo_ + 8192;
  unsigned* wi1lo = wi1hi + 8192;
  unsigned* wi2f  = wi1lo + 8192;
  unsigned* mhi   = wi2f + 4096;
  unsigned* mlo   = mhi + 4096;
  int* rank = (int*)Mpart;  // Mpart dead during CSR build; E ints fit in 16.8MB

  const int NCH = (n + CH - 1) / CH;

  // ---- weight prep (once per launch) ----
  k_prepW<<<32, 256, 0, stream>>>(W0, w0hi, w0lo);
  k_prepW<<<32, 256, 0, stream>>>(W1, w1hi_, w1lo_);
  k_prepW<<<32, 256, 0, stream>>>(Wi1, wi1hi, wi1lo);
  k_prepWs<<<16, 256, 0, stream>>>(Wi2, wi2f);

  // ---- CSR build: rank-hist -> scans -> atomic-free place ----
  hipMemsetAsync(cnt, 0, (size_t)n * sizeof(int), stream);
  k_hist2<<<2048, 256, 0, stream>>>(erow, cnt, rank, E);
  k_chunksum<<<NCH, 256, 0, stream>>>(cnt, csum, n);
  k_chunkscan<<<1, 256, 0, stream>>>(csum, coff, NCH);
  k_rowptr<<<NCH, 256, 0, stream>>>(cnt, coff, rowptr, n, E);
  k_place<<<2048, 256, 0, stream>>>(erow, ecol, eval, rank, rowptr, erec, E);

  const int g_gm  = (n + 255) / 256;   // 8 waves x 32 rows
  const int g_c1m = (n + 127) / 128;   // 8 waves x 16 rows
  const int g_fin = (n + 127) / 128;   // 8 waves x 16 rows

  for (int L = 0; L < 2; ++L) {
    const unsigned* Whi = (L == 0) ? w0hi : w1hi_;
    const unsigned* Wlo = (L == 0) ? w0lo : w1lo_;
    const float* Xin = (L == 0) ? emb : xb;
    k_gemm_mfma<<<g_gm, 512, 0, stream>>>(Xin, Whi, Wlo, Ybf, n);
    k_spmm_csr<<<2048, 256, 0, stream>>>(rowptr, erec, (const unsigned*)Ybf, xb, n);
    k_c1_mfma<<<g_c1m, 512, 0, stream>>>(xb, wi1hi, wi1lo, wi2f, adj, H1g, trow, n);
    k_c2<<<NBLK_C2, 1024, 0, stream>>>(xb, trow, H1g, Mpart, n);
    k_dred1<<<1024, 256, 0, stream>>>(Mpart, Mp2);
    k_dred2p<<<16, 256, 0, stream>>>(Mp2, mhi, mlo);
    k_fin_mfma<<<g_fin, 512, 0, stream>>>(H1g, mhi, mlo, emb, xb, out, n,
                                          (L == 0) ? 1 : 0, (L == 1) ? 1 : 0);
  }
}

// Round 16
// 646.301 us; speedup vs baseline: 1.1505x; 1.0003x over previous
//
#include <hip/hip_runtime.h>

constexpr int DD = 128;   // emb size
constexpr int KK = 64;    // clusters
constexpr int NBLK_C2 = 512;
constexpr int CH = 512;   // rows per scan chunk

typedef __attribute__((ext_vector_type(8))) short bf16x8;
typedef __attribute__((ext_vector_type(4))) float f32x4;

union U4 { unsigned u[4]; int4 i4; bf16x8 v; };

__device__ inline unsigned bf16_rne(float x) {
  unsigned u = __float_as_uint(x);
  u += 0x7fff + ((u >> 16) & 1);
  return u >> 16;
}
__device__ inline float bf16f(unsigned h) { return __uint_as_float(h << 16); }
__device__ inline void split2(float a, float b, unsigned& hi, unsigned& lo) {
  const unsigned h0 = bf16_rne(a), h1 = bf16_rne(b);
  const unsigned l0 = bf16_rne(a - bf16f(h0)), l1 = bf16_rne(b - bf16f(h1));
  hi = h0 | (h1 << 16);
  lo = l0 | (l1 << 16);
}

// ---- weight prep: frag-ordered split bf16. out idx = ((ks*nt+t)*64+l)*4+j ---
__global__ void k_prepW(const float* __restrict__ W, unsigned* __restrict__ Whi,
                        unsigned* __restrict__ Wlo) {  // 128x128, nt=8
  const int id = blockIdx.x * 256 + threadIdx.x;  // 8192
  const int j = id & 3, l = (id >> 2) & 63, t = (id >> 8) & 7, ks = id >> 11;
  const int k0 = 32 * ks + 8 * (l >> 4) + 2 * j;
  const int col = 16 * t + (l & 15);
  const float e0 = W[k0 * 128 + col], e1 = W[(k0 + 1) * 128 + col];
  unsigned hi, lo;
  split2(e0, e1, hi, lo);
  Whi[id] = hi;
  Wlo[id] = lo;
}

__global__ void k_prepWs(const float* __restrict__ W, unsigned* __restrict__ Wf) {
  const int id = blockIdx.x * 256 + threadIdx.x;  // 4096 (128x64, nt=4)
  const int j = id & 3, l = (id >> 2) & 63, t = (id >> 8) & 3, ks = id >> 10;
  const int k0 = 32 * ks + 8 * (l >> 4) + 2 * j;
  const int col = 16 * t + (l & 15);
  const unsigned h0 = bf16_rne(W[k0 * 64 + col]);
  const unsigned h1 = bf16_rne(W[(k0 + 1) * 64 + col]);
  Wf[id] = h0 | (h1 << 16);
}

// ---------------- Y(bf16) = X @ W via MFMA bf16x3 split ---------------------
__global__ __launch_bounds__(512) void k_gemm_mfma(const float* __restrict__ X,
                                                   const unsigned* __restrict__ Whi,
                                                   const unsigned* __restrict__ Wlo,
                                                   unsigned short* __restrict__ Yb,
                                                   int n) {
  __shared__ unsigned sb[2 * 8192];  // hi | lo, 64 KB
  {
    const int t = threadIdx.x;
    uint4* d0 = (uint4*)sb;
    const uint4* s0 = (const uint4*)Whi;
#pragma unroll
    for (int i = 0; i < 4; ++i) d0[t + 512 * i] = s0[t + 512 * i];
    uint4* d1 = (uint4*)(sb + 8192);
    const uint4* s1 = (const uint4*)Wlo;
#pragma unroll
    for (int i = 0; i < 4; ++i) d1[t + 512 * i] = s1[t + 512 * i];
  }
  __syncthreads();
  const int wave = threadIdx.x >> 6, lane = threadIdx.x & 63;
  const int l15 = lane & 15, lhi = lane >> 4;
  const int row0 = blockIdx.x * 256 + wave * 32;
  if (row0 >= n) return;
  f32x4 acc[2][8];
#pragma unroll
  for (int rt = 0; rt < 2; ++rt)
#pragma unroll
    for (int t = 0; t < 8; ++t) acc[rt][t] = (f32x4){0.f, 0.f, 0.f, 0.f};
#pragma unroll
  for (int ks = 0; ks < 4; ++ks) {
    U4 ah[2], al[2];
#pragma unroll
    for (int rt = 0; rt < 2; ++rt) {
      int r = row0 + rt * 16 + l15;
      if (r >= n) r = n - 1;
      const float4 x0 = *(const float4*)&X[(size_t)r * DD + ks * 32 + lhi * 8];
      const float4 x1 = *(const float4*)&X[(size_t)r * DD + ks * 32 + lhi * 8 + 4];
      split2(x0.x, x0.y, ah[rt].u[0], al[rt].u[0]);
      split2(x0.z, x0.w, ah[rt].u[1], al[rt].u[1]);
      split2(x1.x, x1.y, ah[rt].u[2], al[rt].u[2]);
      split2(x1.z, x1.w, ah[rt].u[3], al[rt].u[3]);
    }
#pragma unroll
    for (int t = 0; t < 8; ++t) {
      U4 bh, bl;
      const int off = ((ks * 8 + t) * 64 + lane) * 4;
      bh.i4 = *(const int4*)&sb[off];
      bl.i4 = *(const int4*)&sb[8192 + off];
#pragma unroll
      for (int rt = 0; rt < 2; ++rt) {
        acc[rt][t] = __builtin_amdgcn_mfma_f32_16x16x32_bf16(ah[rt].v, bh.v, acc[rt][t], 0, 0, 0);
        acc[rt][t] = __builtin_amdgcn_mfma_f32_16x16x32_bf16(al[rt].v, bh.v, acc[rt][t], 0, 0, 0);
        acc[rt][t] = __builtin_amdgcn_mfma_f32_16x16x32_bf16(ah[rt].v, bl.v, acc[rt][t], 0, 0, 0);
      }
    }
  }
#pragma unroll
  for (int rt = 0; rt < 2; ++rt)
#pragma unroll
    for (int rr = 0; rr < 4; ++rr) {
      const int row = row0 + rt * 16 + lhi * 4 + rr;
      if (row < n) {
#pragma unroll
        for (int t = 0; t < 8; ++t)
          Yb[(size_t)row * DD + t * 16 + l15] =
              (unsigned short)bf16_rne(acc[rt][t][rr]);
      }
    }
}

// ---------------- CSR build: rank-hist -> scan -> atomic-free place --------
__global__ void k_hist2(const int* __restrict__ er, int* __restrict__ cnt,
                        int* __restrict__ rank, int E) {
  for (long e = (long)blockIdx.x * blockDim.x + threadIdx.x; e < E;
       e += (long)gridDim.x * blockDim.x)
    rank[e] = atomicAdd(&cnt[er[e]], 1);
}

__global__ __launch_bounds__(256) void k_chunksum(const int* __restrict__ cnt,
                                                  int* __restrict__ csum, int n) {
  const int c = blockIdx.x, t = threadIdx.x;
  const int i0 = c * CH + 2 * t;
  int s2 = 0;
  if (i0 < n) s2 += cnt[i0];
  if (i0 + 1 < n) s2 += cnt[i0 + 1];
#pragma unroll
  for (int off = 32; off >= 1; off >>= 1) s2 += __shfl_xor(s2, off);
  __shared__ int ws_[4];
  if ((t & 63) == 0) ws_[t >> 6] = s2;
  __syncthreads();
  if (t == 0) csum[c] = ws_[0] + ws_[1] + ws_[2] + ws_[3];
}

__global__ __launch_bounds__(256) void k_chunkscan(const int* __restrict__ csum,
                                                   int* __restrict__ coff, int nch) {
  __shared__ int s[256];
  const int t = threadIdx.x;
  const int v = (t < nch) ? csum[t] : 0;
  s[t] = v;
  __syncthreads();
  for (int off = 1; off < 256; off <<= 1) {
    const int u = (t >= off) ? s[t - off] : 0;
    __syncthreads();
    s[t] += u;
    __syncthreads();
  }
  coff[t] = s[t] - v;   // exclusive
}

__global__ __launch_bounds__(256) void k_rowptr(const int* __restrict__ cnt,
                                                const int* __restrict__ coff,
                                                int* __restrict__ rowptr,
                                                int n, int E) {
  const int c = blockIdx.x, t = threadIdx.x;
  const int i0 = c * CH + 2 * t, i1 = i0 + 1;
  const int v0 = (i0 < n) ? cnt[i0] : 0;
  const int v1 = (i1 < n) ? cnt[i1] : 0;
  __shared__ int s[256];
  const int s2 = v0 + v1;
  s[t] = s2;
  __syncthreads();
  for (int off = 1; off < 256; off <<= 1) {
    const int u = (t >= off) ? s[t - off] : 0;
    __syncthreads();
    s[t] += u;
    __syncthreads();
  }
  const int excl = s[t] - s2 + coff[c];
  if (i0 < n) rowptr[i0] = excl;
  if (i1 < n) rowptr[i1] = excl + v0;
  if (c == 0 && t == 0) rowptr[n] = E;
}

// place: erec[rowptr[r] + rank[e]] = {col, val}. No atomics, max MLP.
__global__ void k_place(const int* __restrict__ er, const int* __restrict__ ec,
                        const float* __restrict__ ev, const int* __restrict__ rank,
                        const int* __restrict__ rowptr, int2* __restrict__ erec,
                        int E) {
  for (long e = (long)blockIdx.x * blockDim.x + threadIdx.x; e < E;
       e += (long)gridDim.x * blockDim.x) {
    const int r = er[e];
    erec[rowptr[r] + rank[e]] = make_int2(ec[e], __float_as_int(ev[e]));
  }
}

// ---------------- SPMM (CSR): one wave per row, bf16 gather, 4x MLP -------
__global__ __launch_bounds__(256) void k_spmm_csr(const int* __restrict__ rowptr,
                                                  const int2* __restrict__ erec,
                                                  const unsigned* __restrict__ Yb,
                                                  float* __restrict__ Xo, int n) {
  const int lane = threadIdx.x & 63;
  const int c0 = 2 * lane;
  const long gw = (long)blockIdx.x * 4 + (threadIdx.x >> 6);
  const long nw = (long)gridDim.x * 4;
  for (long row = gw; row < n; row += nw) {
    const int b = rowptr[row], e2 = rowptr[row + 1];  // uniform -> s_load
    float a0 = 0.f, a1 = 0.f, b0 = 0.f, b1 = 0.f;
    float c00 = 0.f, c1 = 0.f, d0 = 0.f, d1 = 0.f;
    int e = b;
    for (; e + 4 <= e2; e += 4) {  // 4 independent gathers in flight
      const int2 r0 = erec[e], r1 = erec[e + 1];
      const int2 r2 = erec[e + 2], r3 = erec[e + 3];  // 32B uniform s_load
      const unsigned q0 = Yb[(size_t)r0.x * (DD / 2) + lane];
      const unsigned q1 = Yb[(size_t)r1.x * (DD / 2) + lane];
      const unsigned q2 = Yb[(size_t)r2.x * (DD / 2) + lane];
      const unsigned q3 = Yb[(size_t)r3.x * (DD / 2) + lane];
      const float v0 = __int_as_float(r0.y), v1 = __int_as_float(r1.y);
      const float v2 = __int_as_float(r2.y), v3 = __int_as_float(r3.y);
      a0 = fmaf(v0, __uint_as_float(q0 << 16), a0);
      a1 = fmaf(v0, __uint_as_float(q0 & 0xffff0000u), a1);
      b0 = fmaf(v1, __uint_as_float(q1 << 16), b0);
      b1 = fmaf(v1, __uint_as_float(q1 & 0xffff0000u), b1);
      c00 = fmaf(v2, __uint_as_float(q2 << 16), c00);
      c1 = fmaf(v2, __uint_as_float(q2 & 0xffff0000u), c1);
      d0 = fmaf(v3, __uint_as_float(q3 << 16), d0);
      d1 = fmaf(v3, __uint_as_float(q3 & 0xffff0000u), d1);
    }
    for (; e + 2 <= e2; e += 2) {
      const int2 r0 = erec[e], r1 = erec[e + 1];
      const float v0 = __int_as_float(r0.y), v1 = __int_as_float(r1.y);
      const unsigned q0 = Yb[(size_t)r0.x * (DD / 2) + lane];
      const unsigned q1 = Yb[(size_t)r1.x * (DD / 2) + lane];
      a0 = fmaf(v0, __uint_as_float(q0 << 16), a0);
      a1 = fmaf(v0, __uint_as_float(q0 & 0xffff0000u), a1);
      b0 = fmaf(v1, __uint_as_float(q1 << 16), b0);
      b1 = fmaf(v1, __uint_as_float(q1 & 0xffff0000u), b1);
    }
    if (e < e2) {
      const int2 r0 = erec[e];
      const float v = __int_as_float(r0.y);
      const unsigned q = Yb[(size_t)r0.x * (DD / 2) + lane];
      a0 = fmaf(v, __uint_as_float(q << 16), a0);
      a1 = fmaf(v, __uint_as_float(q & 0xffff0000u), a1);
    }
    *(float2*)&Xo[(size_t)row * DD + c0] =
        make_float2((a0 + b0) + (c00 + d0), (a1 + b1) + (c1 + d1));
  }
}

// ---------------- fused: H1 = softmax(relu(X@Wi1 + X) @ Wi2), MFMA --------
__global__ __launch_bounds__(512) void k_c1_mfma(const float* __restrict__ X,
                                                 const unsigned* __restrict__ W1hi,
                                                 const unsigned* __restrict__ W1lo,
                                                 const unsigned* __restrict__ W2f,
                                                 const float* __restrict__ adj,
                                                 float* __restrict__ H1g,
                                                 float* __restrict__ trow, int n) {
  __shared__ unsigned s1[2 * 8192];     // Wi1 frags hi|lo, 64 KB
  __shared__ unsigned s2[4096];         // Wi2 frags, 16 KB
  __shared__ unsigned h1s[8 * 16 * 68]; // 8 waves x (16 rows x 68 u32), 34 KB
  {
    const int t = threadIdx.x;
    uint4* d0 = (uint4*)s1;
    const uint4* sA = (const uint4*)W1hi;
    const uint4* sB = (const uint4*)W1lo;
#pragma unroll
    for (int i = 0; i < 4; ++i) d0[t + 512 * i] = sA[t + 512 * i];
    uint4* d1 = (uint4*)(s1 + 8192);
#pragma unroll
    for (int i = 0; i < 4; ++i) d1[t + 512 * i] = sB[t + 512 * i];
    uint4* d2 = (uint4*)s2;
    const uint4* sC = (const uint4*)W2f;
#pragma unroll
    for (int i = 0; i < 2; ++i) d2[t + 512 * i] = sC[t + 512 * i];
  }
  __syncthreads();
  const int wave = threadIdx.x >> 6, lane = threadIdx.x & 63;
  const int l15 = lane & 15, lhi = lane >> 4;
  unsigned* __restrict__ h1w = h1s + wave * (16 * 68);
  const int row0 = blockIdx.x * 128 + wave * 16;
  if (row0 >= n) return;

  // ---- P1: acc1 = x @ Wi1 (split bf16, 3 MFMA) ----
  U4 ah[4], al[4];
#pragma unroll
  for (int ks = 0; ks < 4; ++ks) {
    int r = row0 + l15;
    if (r >= n) r = n - 1;
    const float4 x0 = *(const float4*)&X[(size_t)r * DD + ks * 32 + lhi * 8];
    const float4 x1 = *(const float4*)&X[(size_t)r * DD + ks * 32 + lhi * 8 + 4];
    split2(x0.x, x0.y, ah[ks].u[0], al[ks].u[0]);
    split2(x0.z, x0.w, ah[ks].u[1], al[ks].u[1]);
    split2(x1.x, x1.y, ah[ks].u[2], al[ks].u[2]);
    split2(x1.z, x1.w, ah[ks].u[3], al[ks].u[3]);
  }
  f32x4 acc1[8];
#pragma unroll
  for (int t = 0; t < 8; ++t) acc1[t] = (f32x4){0.f, 0.f, 0.f, 0.f};
#pragma unroll
  for (int ks = 0; ks < 4; ++ks) {
#pragma unroll
    for (int t = 0; t < 8; ++t) {
      U4 bh, bl;
      const int off = ((ks * 8 + t) * 64 + lane) * 4;
      bh.i4 = *(const int4*)&s1[off];
      bl.i4 = *(const int4*)&s1[8192 + off];
      acc1[t] = __builtin_amdgcn_mfma_f32_16x16x32_bf16(ah[ks].v, bh.v, acc1[t], 0, 0, 0);
      acc1[t] = __builtin_amdgcn_mfma_f32_16x16x32_bf16(al[ks].v, bh.v, acc1[t], 0, 0, 0);
      acc1[t] = __builtin_amdgcn_mfma_f32_16x16x32_bf16(ah[ks].v, bl.v, acc1[t], 0, 0, 0);
    }
  }

  // ---- P2: +x, relu, pack single bf16 into wave-private LDS (stride 136) --
  unsigned short* __restrict__ h16 = (unsigned short*)h1w;
#pragma unroll
  for (int rr = 0; rr < 4; ++rr) {
    int row = row0 + 4 * lhi + rr;
    if (row >= n) row = n - 1;
    const float* __restrict__ xr = X + (size_t)row * DD;
#pragma unroll
    for (int t = 0; t < 8; ++t) {
      float v = acc1[t][rr] + xr[16 * t + l15];
      v = fmaxf(v, 0.f);
      h16[(4 * lhi + rr) * 136 + 16 * t + l15] = (unsigned short)bf16_rne(v);
    }
  }

  // ---- P3: z = H1a @ Wi2 (single bf16) ----
  f32x4 acc3[4];
#pragma unroll
  for (int t = 0; t < 4; ++t) acc3[t] = (f32x4){0.f, 0.f, 0.f, 0.f};
#pragma unroll
  for (int ks = 0; ks < 4; ++ks) {
    U4 a3;
    a3.i4 = *(const int4*)&h1w[l15 * 68 + ks * 16 + lhi * 4];
#pragma unroll
    for (int t = 0; t < 4; ++t) {
      U4 b3;
      b3.i4 = *(const int4*)&s2[((ks * 4 + t) * 64 + lane) * 4];
      acc3[t] = __builtin_amdgcn_mfma_f32_16x16x32_bf16(a3.v, b3.v, acc3[t], 0, 0, 0);
    }
  }

  // ---- P4: row softmax (64 cols = 4 tiles x 16 lanes) ----
#pragma unroll
  for (int rr = 0; rr < 4; ++rr) {
    const int row = row0 + 4 * lhi + rr;
    float z0 = acc3[0][rr], z1 = acc3[1][rr], z2 = acc3[2][rr], z3 = acc3[3][rr];
    float m = fmaxf(fmaxf(z0, z1), fmaxf(z2, z3));
#pragma unroll
    for (int off = 8; off >= 1; off >>= 1) m = fmaxf(m, __shfl_xor(m, off));
    const float p0 = expf(z0 - m), p1 = expf(z1 - m);
    const float p2 = expf(z2 - m), p3 = expf(z3 - m);
    float s = p0 + p1 + p2 + p3;
#pragma unroll
    for (int off = 8; off >= 1; off >>= 1) s += __shfl_xor(s, off);
    const float inv = 1.0f / s;
    if (row < n) {
      float* __restrict__ hr = H1g + (size_t)row * KK;
      hr[l15] = p0 * inv;
      hr[16 + l15] = p1 * inv;
      hr[32 + l15] = p2 * inv;
      hr[48 + l15] = p3 * inv;
      if (l15 == 0) {
        const float a = adj[row];
        trow[row] = a / (a + 1e-8f);
      }
    }
  }
}

// ---------------- per-block partial of M = (H1*t)^T @ X --------------------
__global__ __launch_bounds__(1024, 4) void k_c2(const float* __restrict__ X,
                                                const float* __restrict__ trow,
                                                const float* __restrict__ H1g,
                                                float* __restrict__ Mpart, int n) {
  __shared__ float cmb[3 * 4 * 16 * 2 * 64];  // 96 KB
  const int t = threadIdx.x;
  const int wave = t >> 6, lane = t & 63;
  const int rg = wave >> 2, kg = wave & 3;
  const int kb = kg * 16;
  const int d0 = 2 * lane;
  float macc[16][2];
#pragma unroll
  for (int j = 0; j < 16; ++j) { macc[j][0] = 0.f; macc[j][1] = 0.f; }
  const int bx = blockIdx.x;
  for (long row = (long)bx + 512L * rg; row < n; row += 2048L) {
    const int r = __builtin_amdgcn_readfirstlane((int)row);
    const float tr = trow[r];                         // s_load
    const float2 xv = *(const float2*)&X[(size_t)r * DD + d0];
    const float px0 = tr * xv.x, px1 = tr * xv.y;
    const float* __restrict__ hrow = H1g + (size_t)r * KK + kb;  // s_loads
#pragma unroll
    for (int j = 0; j < 16; ++j) {
      const float hj = hrow[j];
      macc[j][0] = fmaf(hj, px0, macc[j][0]);
      macc[j][1] = fmaf(hj, px1, macc[j][1]);
    }
  }
  if (rg > 0) {
    float* __restrict__ dst = cmb + ((rg - 1) * 4 + kg) * (16 * 2 * 64);
#pragma unroll
    for (int j = 0; j < 16; ++j) {
      dst[(2 * j + 0) * 64 + lane] = macc[j][0];
      dst[(2 * j + 1) * 64 + lane] = macc[j][1];
    }
  }
  __syncthreads();
  if (rg == 0) {
#pragma unroll
    for (int g = 0; g < 3; ++g) {
      const float* __restrict__ src = cmb + (g * 4 + kg) * (16 * 2 * 64);
#pragma unroll
      for (int j = 0; j < 16; ++j) {
        macc[j][0] += src[(2 * j + 0) * 64 + lane];
        macc[j][1] += src[(2 * j + 1) * 64 + lane];
      }
    }
    float* __restrict__ mp = Mpart + (size_t)bx * (KK * DD);
#pragma unroll
    for (int j = 0; j < 16; ++j)
      *(float2*)&mp[(kb + j) * DD + d0] = make_float2(macc[j][0], macc[j][1]);
  }
}

// ---------------- stage-1 fixed-order reduction of M partials --------------
__global__ void k_dred1(const float* __restrict__ Mpart, float* __restrict__ Mp2) {
  const int j = blockIdx.x * blockDim.x + threadIdx.x;  // 262144 threads
  const int i = j & (KK * DD - 1);
  const int c = j >> 13;
  float s = 0.f;
#pragma unroll
  for (int q = 0; q < 16; ++q)
    s += Mpart[(size_t)(c * 16 + q) * (KK * DD) + i];
  Mp2[(size_t)c * (KK * DD) + i] = s;
}

// ---- stage-2 reduction fused with frag prep: Mp2 -> split-bf16 M frags ----
__global__ void k_dred2p(const float* __restrict__ Mp2, unsigned* __restrict__ Mhi,
                         unsigned* __restrict__ Mlo) {
  const int id = blockIdx.x * 256 + threadIdx.x;  // 4096
  const int j = id & 3, l = (id >> 2) & 63, t = (id >> 8) & 7, ks = id >> 11;
  const int k0 = 32 * ks + 8 * (l >> 4) + 2 * j;
  const int col = 16 * t + (l & 15);
  float s0 = 0.f, s1 = 0.f;
#pragma unroll
  for (int c = 0; c < 32; ++c) {
    s0 += Mp2[(size_t)c * (KK * DD) + k0 * DD + col];
    s1 += Mp2[(size_t)c * (KK * DD) + (k0 + 1) * DD + col];
  }
  unsigned hi, lo;
  split2(s0, s1, hi, lo);
  Mhi[id] = hi;
  Mlo[id] = lo;
}

// ------- h = H1 @ M (split-bf16 MFMA); x = h + x; l2-normed outputs --------
// 256-thread blocks (4 waves x 16 rows): 5 blocks/CU (LDS-limited), 20 waves.
__global__ __launch_bounds__(256) void k_fin_mfma(const float* __restrict__ H1g,
                                                  const unsigned* __restrict__ Mhi,
                                                  const unsigned* __restrict__ Mlo,
                                                  const float* __restrict__ emb,
                                                  float* __restrict__ Xb,
                                                  float* __restrict__ out,
                                                  int n, int first, int last) {
  __shared__ unsigned sm[2 * 4096];  // M frags hi|lo, 32 KB
  {
    const int t = threadIdx.x;
    uint4* d0 = (uint4*)sm;
    const uint4* s0 = (const uint4*)Mhi;
#pragma unroll
    for (int i = 0; i < 4; ++i) d0[t + 256 * i] = s0[t + 256 * i];
    uint4* d1 = (uint4*)(sm + 4096);
    const uint4* s1 = (const uint4*)Mlo;
#pragma unroll
    for (int i = 0; i < 4; ++i) d1[t + 256 * i] = s1[t + 256 * i];
  }
  __syncthreads();
  const int wave = threadIdx.x >> 6, lane = threadIdx.x & 63;
  const int l15 = lane & 15, lhi = lane >> 4;
  const size_t hoff = (size_t)n * DD;
  const int row0 = blockIdx.x * 64 + wave * 16;
  if (row0 >= n) return;

  // A frags: 16 H1 rows, K=64, split hi/lo
  U4 ah[2], al[2];
  {
    int ra = row0 + l15;
    if (ra >= n) ra = n - 1;
    const float* __restrict__ hp = H1g + (size_t)ra * KK;
#pragma unroll
    for (int ks = 0; ks < 2; ++ks) {
      const float4 x0 = *(const float4*)&hp[ks * 32 + lhi * 8];
      const float4 x1 = *(const float4*)&hp[ks * 32 + lhi * 8 + 4];
      split2(x0.x, x0.y, ah[ks].u[0], al[ks].u[0]);
      split2(x0.z, x0.w, ah[ks].u[1], al[ks].u[1]);
      split2(x1.x, x1.y, ah[ks].u[2], al[ks].u[2]);
      split2(x1.z, x1.w, ah[ks].u[3], al[ks].u[3]);
    }
  }
  f32x4 acc[8];
#pragma unroll
  for (int t = 0; t < 8; ++t) acc[t] = (f32x4){0.f, 0.f, 0.f, 0.f};
#pragma unroll
  for (int ks = 0; ks < 2; ++ks) {
#pragma unroll
    for (int t = 0; t < 8; ++t) {
      U4 bh, bl;
      const int off = ((ks * 8 + t) * 64 + lane) * 4;
      bh.i4 = *(const int4*)&sm[off];
      bl.i4 = *(const int4*)&sm[4096 + off];
      acc[t] = __builtin_amdgcn_mfma_f32_16x16x32_bf16(ah[ks].v, bh.v, acc[t], 0, 0, 0);
      acc[t] = __builtin_amdgcn_mfma_f32_16x16x32_bf16(al[ks].v, bh.v, acc[t], 0, 0, 0);
      acc[t] = __builtin_amdgcn_mfma_f32_16x16x32_bf16(ah[ks].v, bl.v, acc[t], 0, 0, 0);
    }
  }
  // epilogue: per row (4 per lhi-group), cols 16t+l15
#pragma unroll
  for (int rr = 0; rr < 4; ++rr) {
    const int row = row0 + 4 * lhi + rr;
    const int rc = (row < n) ? row : (n - 1);
    float hh[8], xx[8];
    float sh = 0.f, sx = 0.f;
#pragma unroll
    for (int t = 0; t < 8; ++t) {
      const float xv = Xb[(size_t)rc * DD + 16 * t + l15];
      hh[t] = acc[t][rr];
      xx[t] = hh[t] + xv;
      sh = fmaf(hh[t], hh[t], sh);
      sx = fmaf(xx[t], xx[t], sx);
    }
#pragma unroll
    for (int off = 8; off >= 1; off >>= 1) {  // reduce within 16-lane row group
      sh += __shfl_xor(sh, off);
      sx += __shfl_xor(sx, off);
    }
    const float ih = 0.5f / fmaxf(sqrtf(sh), 1e-12f);
    const float ix = (1.0f / 3.0f) / fmaxf(sqrtf(sx), 1e-12f);
    if (row < n) {
#pragma unroll
      for (int t = 0; t < 8; ++t) {
        const size_t oi = (size_t)row * DD + 16 * t + l15;
        if (!last) Xb[oi] = xx[t];   // xb dead after last layer
        float ci, ch;
        if (first) {
          ci = emb[oi] * (1.0f / 3.0f);
          ch = 0.f;
        } else {
          ci = out[oi];
          ch = out[hoff + oi];
        }
        out[oi] = ci + xx[t] * ix;
        out[hoff + oi] = ch + hh[t] * ih;
      }
    }
  }
}

extern "C" void kernel_launch(void* const* d_in, const int* in_sizes, int n_in,
                              void* d_out, int out_size, void* d_ws, size_t ws_size,
                              hipStream_t stream) {
  const float* adj  = (const float*)d_in[0];
  const int*   erow = (const int*)d_in[1];
  const int*   ecol = (const int*)d_in[2];
  const float* eval = (const float*)d_in[3];
  const float* emb  = (const float*)d_in[4];
  const float* W0   = (const float*)d_in[5];
  const float* W1   = (const float*)d_in[6];
  const float* Wi1  = (const float*)d_in[7];
  const float* Wi2  = (const float*)d_in[8];
  const int n = in_sizes[0];
  const int E = in_sizes[1];
  float* out = (float*)d_out;

  float* xb    = (float*)d_ws;
  float* yb    = xb + (size_t)n * DD;
  unsigned short* Ybf = (unsigned short*)yb;
  float* H1g   = yb + (size_t)n * (DD / 2);  // after Ybf region (Ybf dead by c1)
  float* Mpart = H1g + (size_t)n * KK;
  float* Mp2   = Mpart + (size_t)NBLK_C2 * KK * DD;
  float* Mg    = Mp2 + (size_t)32 * KK * DD;  // (layout keeper)
  int*   cnt    = (int*)(Mg + KK * DD);
  int*   rowptr = cnt + n;
  int*   csum   = rowptr + n + 4;
  int*   coff   = csum + 256;
  int2*  erec   = (int2*)(coff + 256);
  float* trow   = (float*)(erec + E);
  unsigned* w0hi  = (unsigned*)(trow + n);
  unsigned* w0lo  = w0hi + 8192;
  unsigned* w1hi_ = w0lo + 8192;
  unsigned* w1lo_ = w1hi_ + 8192;
  unsigned* wi1hi = w1lo_ + 8192;
  unsigned* wi1lo = wi1hi + 8192;
  unsigned* wi2f  = wi1lo + 8192;
  unsigned* mhi   = wi2f + 4096;
  unsigned* mlo   = mhi + 4096;
  int* rank = (int*)Mpart;  // Mpart dead during CSR build

  const int NCH = (n + CH - 1) / CH;

  // ---- weight prep (once per launch) ----
  k_prepW<<<32, 256, 0, stream>>>(W0, w0hi, w0lo);
  k_prepW<<<32, 256, 0, stream>>>(W1, w1hi_, w1lo_);
  k_prepW<<<32, 256, 0, stream>>>(Wi1, wi1hi, wi1lo);
  k_prepWs<<<16, 256, 0, stream>>>(Wi2, wi2f);

  // ---- CSR build: rank-hist -> scans -> atomic-free place ----
  hipMemsetAsync(cnt, 0, (size_t)n * sizeof(int), stream);
  k_hist2<<<2048, 256, 0, stream>>>(erow, cnt, rank, E);
  k_chunksum<<<NCH, 256, 0, stream>>>(cnt, csum, n);
  k_chunkscan<<<1, 256, 0, stream>>>(csum, coff, NCH);
  k_rowptr<<<NCH, 256, 0, stream>>>(cnt, coff, rowptr, n, E);
  k_place<<<2048, 256, 0, stream>>>(erow, ecol, eval, rank, rowptr, erec, E);

  const int g_gm  = (n + 255) / 256;   // 8 waves x 32 rows
  const int g_c1m = (n + 127) / 128;   // 8 waves x 16 rows
  const int g_fin = (n + 63) / 64;     // 4 waves x 16 rows

  for (int L = 0; L < 2; ++L) {
    const unsigned* Whi = (L == 0) ? w0hi : w1hi_;
    const unsigned* Wlo = (L == 0) ? w0lo : w1lo_;
    const float* Xin = (L == 0) ? emb : xb;
    k_gemm_mfma<<<g_gm, 512, 0, stream>>>(Xin, Whi, Wlo, Ybf, n);
    k_spmm_csr<<<2048, 256, 0, stream>>>(rowptr, erec, (const unsigned*)Ybf, xb, n);
    k_c1_mfma<<<g_c1m, 512, 0, stream>>>(xb, wi1hi, wi1lo, wi2f, adj, H1g, trow, n);
    k_c2<<<NBLK_C2, 1024, 0, stream>>>(xb, trow, H1g, Mpart, n);
    k_dred1<<<1024, 256, 0, stream>>>(Mpart, Mp2);
    k_dred2p<<<16, 256, 0, stream>>>(Mp2, mhi, mlo);
    k_fin_mfma<<<g_fin, 256, 0, stream>>>(H1g, mhi, mlo, emb, xb, out, n,
                                          (L == 0) ? 1 : 0, (L == 1) ? 1 : 0);
  }
}